// Round 16
// baseline (3179.392 us; speedup 1.0000x reference)
//
#include <hip/hip_runtime.h>
#include <hip/hip_fp16.h>

#define N_NODES 100000
#define N_EDGES 3200000
#define BGR 64
#define DIM 16
#define NFP 33
#define ROW1 32
#define EMB 128
#define MAXLEN 3000
#define LOCLEN 2998
#define NF 32
#define KS 8
#define OUTT 121
#define FC_IN 3872
#define BN_EPSV 1e-5f
#define POOL_CHUNK 256
#define POOL_BLKS 391
// binned CSR build
#define NBIN 391
#define BCNT_BLK 512
#define P1_CHUNK 4096
#define P1_BLOCKS 782
#define MAXBIN 9088
// fc K-split
#define NKC 32
#define KCH 121

// ---------------- CSR build ----------------
__global__ void __launch_bounds__(256) k_bincnt(const int* __restrict__ dst,
                                                int* __restrict__ bh) {
    __shared__ int hist[NBIN];
    int t = threadIdx.x, bid = blockIdx.x;
    for (int b = t; b < NBIN; b += 256) hist[b] = 0;
    __syncthreads();
    int e0 = bid * (N_EDGES / BCNT_BLK);
    int e1 = e0 + (N_EDGES / BCNT_BLK);
    for (int e = e0 + t; e < e1; e += 256) atomicAdd(&hist[dst[e] >> 8], 1);
    __syncthreads();
    for (int b = t; b < NBIN; b += 256) bh[b * BCNT_BLK + bid] = hist[b];
}

__global__ void __launch_bounds__(512) k_binscan(const int* __restrict__ bh,
                                                 int* __restrict__ binoff,
                                                 int* __restrict__ bincur) {
    __shared__ int sc[512];
    int t = threadIdx.x;
    int s = 0;
    if (t < NBIN) {
        const int* row = bh + t * BCNT_BLK;
        for (int k = 0; k < BCNT_BLK; k++) s += row[k];
    }
    sc[t] = s;
    __syncthreads();
    for (int off = 1; off < 512; off <<= 1) {
        int v = (t >= off) ? sc[t - off] : 0;
        __syncthreads();
        sc[t] += v;
        __syncthreads();
    }
    int excl = sc[t] - s;
    if (t <= NBIN) binoff[t] = excl;
    if (t < NBIN) bincur[t] = excl;
}

__global__ void __launch_bounds__(256) k_part1(const int* __restrict__ src,
                                               const int* __restrict__ dst,
                                               const float* __restrict__ w,
                                               int* __restrict__ bincur,
                                               int2* __restrict__ tmp_sw) {
    __shared__ int2 srec[P1_CHUNK];
    __shared__ unsigned short sbin[P1_CHUNK];
    __shared__ unsigned short sperm[P1_CHUNK];
    __shared__ int hist[NBIN];
    __shared__ int off[NBIN];
    __shared__ int cur[NBIN];
    __shared__ int base[NBIN];
    __shared__ int sc[512];
    int t = threadIdx.x;
    int g0 = blockIdx.x * P1_CHUNK;
    int cn = N_EDGES - g0; if (cn > P1_CHUNK) cn = P1_CHUNK;
    for (int b = t; b < NBIN; b += 256) hist[b] = 0;
    __syncthreads();
    for (int j = t; j < cn; j += 256) {
        int d = dst[g0 + j];
        int b = d >> 8;
        sbin[j] = (unsigned short)b;
        srec[j] = make_int2(src[g0 + j] | ((d & 255) << 20), __float_as_int(w[g0 + j]));
        atomicAdd(&hist[b], 1);
    }
    __syncthreads();
    sc[t] = (t < NBIN) ? hist[t] : 0;
    sc[256 + t] = (256 + t < NBIN) ? hist[256 + t] : 0;
    __syncthreads();
    for (int o = 1; o <= 256; o <<= 1) {
        int v0 = (t >= o) ? sc[t - o] : 0;
        int v1 = sc[256 + t - o];
        __syncthreads();
        sc[t] += v0;
        sc[256 + t] += v1;
        __syncthreads();
    }
    for (int b = t; b < NBIN; b += 256) {
        int e = sc[b] - hist[b];
        off[b] = e;
        cur[b] = e;
        int c = hist[b];
        base[b] = c ? atomicAdd(&bincur[b], c) : 0;
    }
    __syncthreads();
    for (int j = t; j < cn; j += 256) {
        int p = atomicAdd(&cur[sbin[j]], 1);
        sperm[p] = (unsigned short)j;
    }
    __syncthreads();
    for (int p = t; p < cn; p += 256) {
        int j = sperm[p];
        int b = sbin[j];
        tmp_sw[base[b] + (p - off[b])] = srec[j];
    }
}

// pass 2: per-bin fine sort + ptr; er keeps packed src|dl<<20, fp32 w
__global__ void __launch_bounds__(256) k_part2(const int2* __restrict__ tmp_sw,
                                               const int* __restrict__ binoff,
                                               int2* __restrict__ er,
                                               int* __restrict__ ptr) {
    __shared__ unsigned char sdl[MAXBIN];
    __shared__ unsigned short perm[MAXBIN];
    __shared__ int hist[256];
    __shared__ int cur[256];
    __shared__ int sc[256];
    int t = threadIdx.x, b = blockIdx.x;
    int nlo = b << 8;
    int e0 = binoff[b], e1 = binoff[b + 1];
    int cnt = e1 - e0;
    int stage = cnt < MAXBIN ? cnt : MAXBIN;
    hist[t] = 0;
    __syncthreads();
    for (int j = t; j < stage; j += 256) {
        unsigned char dl = (unsigned char)((tmp_sw[e0 + j].x >> 20) & 255);
        sdl[j] = dl;
        atomicAdd(&hist[dl], 1);
    }
    for (int j = stage + t; j < cnt; j += 256)
        atomicAdd(&hist[(tmp_sw[e0 + j].x >> 20) & 255], 1);
    __syncthreads();
    int v = hist[t];
    sc[t] = v;
    __syncthreads();
    for (int off = 1; off < 256; off <<= 1) {
        int u = (t >= off) ? sc[t - off] : 0;
        __syncthreads();
        sc[t] += u;
        __syncthreads();
    }
    int excl = sc[t] - v;
    cur[t] = excl;
    if (nlo + t < N_NODES) ptr[nlo + t] = e0 + excl;
    if (b == NBIN - 1 && t == 0) ptr[N_NODES] = N_EDGES;
    __syncthreads();
    for (int j = t; j < stage; j += 256) {
        int p = atomicAdd(&cur[sdl[j]], 1);
        perm[p] = (unsigned short)j;
    }
    __syncthreads();
    for (int j = stage + t; j < cnt; j += 256) {
        int2 sw = tmp_sw[e0 + j];
        int p = atomicAdd(&cur[(sw.x >> 20) & 255], 1);
        er[e0 + p] = sw;
    }
    for (int p = t; p < stage; p += 256) {
        er[e0 + p] = tmp_sw[e0 + perm[p]];
    }
}

// ---------------- fp16 conversion of pro_x ----------------
__global__ void k_half1(const float* __restrict__ x, __half* __restrict__ xh,
                        __half* __restrict__ xh32) {
    int i = blockIdx.x * blockDim.x + threadIdx.x;
    if (i < N_NODES * NFP) {
        int n = i / NFP, f = i - n * NFP;
        __half v = __float2half(x[i]);
        if (f < 32) xh[n * ROW1 + f] = v;
        else xh32[n] = v;
    }
}

__device__ __forceinline__ void unpack8(uint4 r, float x[8]) {
    float2 f01 = __half22float2(*(__half2*)&r.x);
    float2 f23 = __half22float2(*(__half2*)&r.y);
    float2 f45 = __half22float2(*(__half2*)&r.z);
    float2 f67 = __half22float2(*(__half2*)&r.w);
    x[0] = f01.x; x[1] = f01.y; x[2] = f23.x; x[3] = f23.y;
    x[4] = f45.x; x[5] = f45.y; x[6] = f67.x; x[7] = f67.y;
}

// BN-partial tail for 512-thread fused layer kernels (nodes on threads 0-255)
__device__ __forceinline__ void tail512(float zv[16], bool act, int t,
                                        float* __restrict__ part) {
    __shared__ float red[4][32];
    float zs[16], zq[16];
    #pragma unroll
    for (int o = 0; o < 16; o++) {
        zs[o] = act ? zv[o] : 0.f;
        zq[o] = act ? zv[o] * zv[o] : 0.f;
    }
    #pragma unroll
    for (int m = 1; m <= 32; m <<= 1) {
        #pragma unroll
        for (int o = 0; o < 16; o++) {
            zs[o] += __shfl_xor(zs[o], m);
            zq[o] += __shfl_xor(zq[o], m);
        }
    }
    int wave = t >> 6, lane = t & 63;
    if (t < 256 && lane == 0) {
        #pragma unroll
        for (int o = 0; o < 16; o++) {
            red[wave][o] = zs[o];
            red[wave][16 + o] = zq[o];
        }
    }
    __syncthreads();
    if (t < 32)
        part[blockIdx.x * 32 + t] = red[0][t] + red[1][t] + red[2][t] + red[3][t];
}

__device__ __forceinline__ void store_zh(__half* __restrict__ zh, int n, float zv[16]) {
    __half2 p[8];
    #pragma unroll
    for (int j = 0; j < 8; j++) p[j] = __floats2half2_rn(zv[2 * j], zv[2 * j + 1]);
    *(uint4*)(zh + n * DIM) = *(uint4*)&p[0];
    *(uint4*)(zh + n * DIM + 8) = *(uint4*)&p[4];
}

// ---------------- fused layer 1: edge-parallel bin-block agg + MLP ----------------
#define A1S 35   // acc stride (gcd(35-32=3,32)=1 -> uniform banks)
__global__ void __launch_bounds__(512) k_layer1(
    const __half* __restrict__ xh, const __half* __restrict__ xh32,
    const int* __restrict__ binoff, const int2* __restrict__ er,
    const float* __restrict__ ew, const float* __restrict__ ebv,
    const float* __restrict__ epsp,
    const float* __restrict__ W1, const float* __restrict__ b1,
    const float* __restrict__ W2, const float* __restrict__ b2,
    __half* __restrict__ zout, float* __restrict__ part) {
    __shared__ float acc[256 * A1S];
    __shared__ float W1s[NFP * 16], W2s[256], b1s[16], b2s[16];
    int t = threadIdx.x, b = blockIdx.x;
    for (int j = t; j < 256 * A1S; j += 512) acc[j] = 0.f;
    for (int j = t; j < NFP * 16; j += 512) W1s[j] = W1[j];
    if (t < 256) W2s[t] = W2[t];
    if (t >= 256 && t < 272) { b1s[t - 256] = b1[t - 256]; b2s[t - 256] = b2[t - 256]; }
    float rew[NFP], reb[NFP];
    #pragma unroll
    for (int f = 0; f < NFP; f++) { rew[f] = ew[f]; reb[f] = ebv[f]; }
    __syncthreads();
    int e0 = binoff[b], e1 = binoff[b + 1];
    for (int e = e0 + t; e < e1; e += 512) {
        int2 rec = er[e];
        int s = rec.x & 0x1FFFF;
        int dl = (rec.x >> 20) & 255;
        float w = __int_as_float(rec.y);
        const __half* xr = xh + s * ROW1;
        float* ap = acc + dl * A1S;
        #pragma unroll
        for (int c = 0; c < 4; c++) {
            uint4 r = *(const uint4*)(xr + c * 8);
            float x[8];
            unpack8(r, x);
            #pragma unroll
            for (int j = 0; j < 8; j++) {
                float v = fmaxf(x[j] + fmaf(w, rew[c * 8 + j], reb[c * 8 + j]), 0.f);
                atomicAdd(&ap[c * 8 + j], v);
            }
        }
        float v32 = fmaxf(__half2float(xh32[s]) + fmaf(w, rew[32], reb[32]), 0.f);
        atomicAdd(&ap[32], v32);
    }
    __syncthreads();
    int n = (b << 8) + (t & 255);
    bool act = (t < 256) && (n < N_NODES);
    float zv[16];
    if (act) {
        float ep = 1.f + epsp[0];
        float hv[NFP];
        const __half* xr = xh + n * ROW1;
        const float* ap = acc + (t & 255) * A1S;
        #pragma unroll
        for (int c = 0; c < 4; c++) {
            uint4 r = *(const uint4*)(xr + c * 8);
            float x[8];
            unpack8(r, x);
            #pragma unroll
            for (int j = 0; j < 8; j++) hv[c * 8 + j] = ep * x[j] + ap[c * 8 + j];
        }
        hv[32] = ep * __half2float(xh32[n]) + ap[32];
        float tv[16];
        #pragma unroll
        for (int o = 0; o < 16; o++) {
            float s = b1s[o];
            #pragma unroll
            for (int f = 0; f < NFP; f++) s += hv[f] * W1s[f * 16 + o];
            tv[o] = fmaxf(s, 0.f);
        }
        #pragma unroll
        for (int o = 0; o < 16; o++) {
            float s = b2s[o];
            #pragma unroll
            for (int f = 0; f < 16; f++) s += tv[f] * W2s[f * 16 + o];
            zv[o] = fmaxf(s, 0.f);
        }
        store_zh(zout, n, zv);
    }
    tail512(zv, act, t, part);
}

// ---------------- fused layers 2-5: edge-parallel bin-block agg (BN folded) + MLP ----------------
#define A16S 17  // acc stride (gcd(17,32)=1)
__global__ void __launch_bounds__(512) k_layer16(
    const __half* __restrict__ zin, const int* __restrict__ binoff,
    const int2* __restrict__ er,
    const float* __restrict__ ew, const float* __restrict__ ebv,
    const float* __restrict__ epsp,
    const float* __restrict__ bnstat, const float* __restrict__ gamma,
    const float* __restrict__ beta,
    const float* __restrict__ W1, const float* __restrict__ b1,
    const float* __restrict__ W2, const float* __restrict__ b2,
    __half* __restrict__ zout, float* __restrict__ part) {
    __shared__ float acc[256 * A16S];
    __shared__ float W1s[256], W2s[256], b1s[16], b2s[16];
    __shared__ float s_sc[16], s_sh[16];
    int t = threadIdx.x, b = blockIdx.x;
    for (int j = t; j < 256 * A16S; j += 512) acc[j] = 0.f;
    if (t < 256) W1s[t] = W1[t];
    else W2s[t - 256] = W2[t - 256];
    if (t < 16) { b1s[t] = b1[t]; b2s[t] = b2[t]; }
    if (t >= 16 && t < 32) {
        int f = t - 16;
        const float invn = 1.f / (float)N_NODES;
        float mu = bnstat[f] * invn;
        float var = bnstat[16 + f] * invn - mu * mu;
        float sc = gamma[f] * rsqrtf(var + BN_EPSV);
        s_sc[f] = sc;
        s_sh[f] = beta[f] - mu * sc;
    }
    __syncthreads();
    float rsc[16], rcb[16], rew[16];
    #pragma unroll
    for (int f = 0; f < 16; f++) {
        rsc[f] = s_sc[f];
        rcb[f] = s_sh[f] + ebv[f];
        rew[f] = ew[f];
    }
    int e0 = binoff[b], e1 = binoff[b + 1];
    for (int e = e0 + t; e < e1; e += 512) {
        int2 rec = er[e];
        int s = rec.x & 0x1FFFF;
        int dl = (rec.x >> 20) & 255;
        float w = __int_as_float(rec.y);
        uint4 r0 = *(const uint4*)(zin + s * DIM);
        uint4 r1 = *(const uint4*)(zin + s * DIM + 8);
        float x[16];
        unpack8(r0, x);
        unpack8(r1, x + 8);
        float* ap = acc + dl * A16S;
        #pragma unroll
        for (int f = 0; f < 16; f++) {
            float v = fmaxf(fmaf(x[f], rsc[f], fmaf(w, rew[f], rcb[f])), 0.f);
            atomicAdd(&ap[f], v);
        }
    }
    __syncthreads();
    int n = (b << 8) + (t & 255);
    bool act = (t < 256) && (n < N_NODES);
    float zv[16];
    if (act) {
        float ep = 1.f + epsp[0];
        uint4 r0 = *(const uint4*)(zin + n * DIM);
        uint4 r1 = *(const uint4*)(zin + n * DIM + 8);
        float xs[16];
        unpack8(r0, xs);
        unpack8(r1, xs + 8);
        const float* ap = acc + (t & 255) * A16S;
        float hv[16];
        #pragma unroll
        for (int f = 0; f < 16; f++)
            hv[f] = ep * fmaf(xs[f], s_sc[f], s_sh[f]) + ap[f];
        float tv[16];
        #pragma unroll
        for (int o = 0; o < 16; o++) {
            float s = b1s[o];
            #pragma unroll
            for (int f = 0; f < 16; f++) s += hv[f] * W1s[f * 16 + o];
            tv[o] = fmaxf(s, 0.f);
        }
        #pragma unroll
        for (int o = 0; o < 16; o++) {
            float s = b2s[o];
            #pragma unroll
            for (int f = 0; f < 16; f++) s += tv[f] * W2s[f * 16 + o];
            zv[o] = fmaxf(s, 0.f);
        }
        store_zh(zout, n, zv);
    }
    tail512(zv, act, t, part);
}

// ---------------- reduce block partials -> bnstat[32] ----------------
__global__ void __launch_bounds__(1024) k_bnred(const float* __restrict__ part,
                                                float* __restrict__ bnstat) {
    __shared__ float red[1024];
    int t = threadIdx.x;
    int f = t & 31, g = t >> 5;
    float s = 0.f;
    for (int i = g; i < NBIN; i += 32) s += part[i * 32 + f];
    red[t] = s;
    __syncthreads();
    for (int off = 512; off >= 32; off >>= 1) {
        if (t < off) red[t] += red[t + off];
        __syncthreads();
    }
    if (t < 32) bnstat[t] = red[t];
}

// ---------------- pooling with BN folded in ----------------
__global__ void __launch_bounds__(256) k_pool(const __half* __restrict__ zh,
                                              const int* __restrict__ batch,
                                              const float* __restrict__ bnstat,
                                              const float* __restrict__ gamma,
                                              const float* __restrict__ beta,
                                              float* __restrict__ gsum,
                                              float* __restrict__ gcnt) {
    __shared__ float lsum[BGR * DIM];
    __shared__ float lcnt[BGR];
    int t = threadIdx.x;
    for (int j = t; j < BGR * DIM; j += 256) lsum[j] = 0.f;
    if (t < BGR) lcnt[t] = 0.f;
    __syncthreads();
    int f = t & 15, r = t >> 4;
    const float invn = 1.f / (float)N_NODES;
    float mu = bnstat[f] * invn;
    float var = bnstat[DIM + f] * invn - mu * mu;
    float sc = gamma[f] * rsqrtf(var + BN_EPSV);
    float sh = beta[f] - mu * sc;
    int start = blockIdx.x * POOL_CHUNK;
    float acc = 0.f, cacc = 0.f;
    int cur = -1;
    for (int i = 0; i < POOL_CHUNK / 16; i++) {
        int n = start + r + i * 16;
        if (n >= N_NODES) break;
        int b = batch[n];
        if (b != cur) {
            if (cur >= 0) {
                atomicAdd(&lsum[cur * DIM + f], acc);
                if (f == 0) atomicAdd(&lcnt[cur], cacc);
            }
            cur = b; acc = 0.f; cacc = 0.f;
        }
        acc += fmaf(__half2float(zh[n * DIM + f]), sc, sh);
        cacc += 1.f;
    }
    if (cur >= 0) {
        atomicAdd(&lsum[cur * DIM + f], acc);
        if (f == 0) atomicAdd(&lcnt[cur], cacc);
    }
    __syncthreads();
    for (int j = t; j < BGR * DIM; j += 256) {
        float v = lsum[j];
        if (v != 0.f) atomicAdd(&gsum[j], v);
    }
    if (t < BGR) {
        float v = lcnt[t];
        if (v != 0.f) atomicAdd(&gcnt[t], v);
    }
}

__global__ void k_xp(const float* __restrict__ gsum, const float* __restrict__ gcnt,
                     const float* __restrict__ w, const float* __restrict__ bias,
                     float* __restrict__ out) {
    int b = blockIdx.x;
    int e = threadIdx.x;
    float inv = 1.f / fmaxf(gcnt[b], 1.f);
    float acc = bias[e];
    #pragma unroll
    for (int f = 0; f < DIM; f++) acc += gsum[b * DIM + f] * inv * w[f * EMB + e];
    out[b * EMB + e] = fmaxf(acc, 0.f);
}

// ---------------- RNA ----------------
__global__ void __launch_bounds__(256) k_bucket(const int* __restrict__ tok, int L, int V,
                                                int* __restrict__ blist,
                                                int* __restrict__ bptr) {
    __shared__ int hist[65];
    __shared__ int cursor[65];
    int b = blockIdx.x, t = threadIdx.x;
    if (t < V) hist[t] = 0;
    __syncthreads();
    for (int l = t; l < L; l += 256) atomicAdd(&hist[tok[b * L + l]], 1);
    __syncthreads();
    if (t == 0) {
        int run = 0;
        for (int v = 0; v < V; v++) {
            cursor[v] = run;
            bptr[b * (V + 1) + v] = run;
            run += hist[v];
        }
        bptr[b * (V + 1) + V] = run;
    }
    __syncthreads();
    for (int l = t; l < L; l += 256) {
        int v = tok[b * L + l];
        int p = atomicAdd(&cursor[v], 1);
        blist[b * L + p] = l;
    }
}

__global__ void __launch_bounds__(256) k_wsum(const int* __restrict__ blist,
                                              const int* __restrict__ bptr,
                                              const float* __restrict__ cw,
                                              float* __restrict__ W, int L, int V) {
    int b = blockIdx.x, v = blockIdx.y;
    int t = threadIdx.x, o = t >> 3, k = t & 7;
    int s = bptr[b * (V + 1) + v], e = bptr[b * (V + 1) + v + 1];
    __shared__ int tk[256];
    const float* cwp = cw + o * (L * KS) + k;
    float acc = 0.f;
    for (int j0 = s; j0 < e; j0 += 256) {
        int lim = e - j0; if (lim > 256) lim = 256;
        __syncthreads();
        if (t < lim) tk[t] = blist[b * L + j0 + t];
        __syncthreads();
        for (int j = 0; j < lim; j++) acc += cwp[tk[j] * KS];
    }
    W[((b * NF + o) * V + v) * KS + k] = acc;
}

__global__ void k_y(const float* __restrict__ Wg, const float* __restrict__ Wl,
                    const float* __restrict__ emb1, const float* __restrict__ emb2,
                    const float* __restrict__ cb1, const float* __restrict__ cb2,
                    float* __restrict__ yg, float* __restrict__ yl) {
    int which = blockIdx.y;
    int bo = blockIdx.x;
    int b = bo >> 5, o = bo & 31;
    int t = threadIdx.x;  // 128
    const float* W = which ? Wl : Wg;
    const float* emb = which ? emb2 : emb1;
    const float* cb = which ? cb2 : cb1;
    float* y = which ? yl : yg;
    int V = which ? 65 : 5;
    __shared__ float Wsh[65 * KS];
    const float* Wrow = W + (b * NF + o) * V * KS;
    for (int j = t; j < V * KS; j += 128) Wsh[j] = Wrow[j];
    __syncthreads();
    if (t < OUTT) {
        float acc = cb[o];
        for (int v = 0; v < V; v++) {
            const float* ep = emb + v * EMB + t;
            #pragma unroll
            for (int k = 0; k < KS; k++) acc += Wsh[v * KS + k] * ep[k];
        }
        y[(b * NF + o) * OUTT + t] = acc;
    }
}

__global__ void __launch_bounds__(128) k_fcpart(const float* __restrict__ yg,
                                                const float* __restrict__ yl,
                                                const float* __restrict__ w,
                                                float* __restrict__ partial) {
    int b = blockIdx.x, which = blockIdx.y, kc = blockIdx.z;
    const float* y = which ? yl : yg;
    int e = threadIdx.x;
    __shared__ float ych[KCH];
    int j0 = kc * KCH;
    if (e < KCH) ych[e] = y[b * FC_IN + j0 + e];
    __syncthreads();
    float acc = 0.f;
    #pragma unroll 4
    for (int jj = 0; jj < KCH; jj++) acc += ych[jj] * w[(j0 + jj) * EMB + e];
    partial[((which * BGR + b) * NKC + kc) * EMB + e] = acc;
}

__global__ void k_fcred(const float* __restrict__ partial, const float* __restrict__ bias,
                        float* __restrict__ out) {
    int b = blockIdx.x;
    int e = threadIdx.x;
    const float* pg = partial + b * NKC * EMB + e;
    const float* pl = partial + (BGR + b) * NKC * EMB + e;
    float ag = bias[e], al = bias[e];
    #pragma unroll
    for (int k = 0; k < NKC; k++) { ag += pg[k * EMB]; al += pl[k * EMB]; }
    out[b * EMB + e] = 0.5f * (ag + al);
}

extern "C" void kernel_launch(void* const* d_in, const int* in_sizes, int n_in,
                              void* d_out, int out_size, void* d_ws, size_t ws_size,
                              hipStream_t stream) {
    const float* pro_x = (const float*)d_in[0];
    const int* eidx = (const int*)d_in[1];
    const int* esrc = eidx;
    const int* edst = eidx + N_EDGES;
    const float* pw = (const float*)d_in[2];
    const int* batch = (const int*)d_in[3];
    const int* rg = (const int*)d_in[4];
    const int* rl = (const int*)d_in[5];
    const float* g1_w1 = (const float*)d_in[6];
    const float* g1_b1 = (const float*)d_in[7];
    const float* g1_w2 = (const float*)d_in[8];
    const float* g1_b2 = (const float*)d_in[9];
    const float* g1_ew = (const float*)d_in[10];
    const float* g1_eb = (const float*)d_in[11];
    const float* g1_eps = (const float*)d_in[12];
    const float* g_w1 = (const float*)d_in[13];
    const float* g_b1 = (const float*)d_in[14];
    const float* g_w2 = (const float*)d_in[15];
    const float* g_b2 = (const float*)d_in[16];
    const float* g_ew = (const float*)d_in[17];
    const float* g_eb = (const float*)d_in[18];
    const float* g_eps = (const float*)d_in[19];
    const float* bn_gamma = (const float*)d_in[20];
    const float* bn_beta = (const float*)d_in[21];
    const float* fc1_xp_w = (const float*)d_in[22];
    const float* fc1_xp_b = (const float*)d_in[23];
    const float* emb1 = (const float*)d_in[24];
    const float* emb2 = (const float*)d_in[25];
    const float* convr1_w = (const float*)d_in[26];
    const float* convr1_b = (const float*)d_in[27];
    const float* convr2_w = (const float*)d_in[28];
    const float* convr2_b = (const float*)d_in[29];
    const float* fcxr_w = (const float*)d_in[30];
    const float* fcxr_b = (const float*)d_in[31];
    float* out = (float*)d_out;

    // persistent buffers
    float* wsf = (float*)d_ws;
    int* ptr       = (int*)wsf;        wsf += 100128;
    int* binoff    = (int*)wsf;        wsf += 512;
    int* bincur    = (int*)wsf;        wsf += 512;
    int2* er       = (int2*)wsf;       wsf += 2 * N_EDGES;
    float* stats   = wsf;              wsf += 1280;
    // union region: CSR temporaries alias post-CSR buffers (stream-ordered)
    float* un = wsf;
    int2* tmp_sw = (int2*)un;                   // [0, 6.4M words)
    int* bh      = (int*)(un + 7200000);
    __half* zhA  = (__half*)un;                 // [0, 800K words)
    __half* zhB  = (__half*)(un + 800000);      // [800K, 1.6M)
    __half* xh1  = (__half*)(un + 1600000);     // [1.6M, 3.2M)
    __half* xh32 = (__half*)(un + 3200000);     // [3.2M, 3.25M)
    float* bpart = un + 3300000;                // NBIN*32
    float* Wg    = un + 3400000;
    float* Wl    = un + 3482000;
    float* yg    = un + 4550000;
    float* yl    = un + 4800000;
    int* blg     = (int*)(un + 5050000);
    int* bll     = (int*)(un + 5242000);
    int* bpg     = (int*)(un + 5434000);
    int* bpl     = (int*)(un + 5435000);
    float* fcpart = un + 5440000;               // 524288 words
    float* gsum   = stats;
    float* gcnt   = stats + 1024;
    float* bnstat = stats + 1088;

    hipMemsetAsync(stats, 0, 1280 * sizeof(float), stream);

    // CSR build (binned two-phase)
    k_bincnt<<<BCNT_BLK, 256, 0, stream>>>(edst, bh);
    k_binscan<<<1, 512, 0, stream>>>(bh, binoff, bincur);
    k_part1<<<P1_BLOCKS, 256, 0, stream>>>(esrc, edst, pw, bincur, tmp_sw);
    k_part2<<<NBIN, 256, 0, stream>>>(tmp_sw, binoff, er, ptr);

    // pro_x -> fp16 rows
    k_half1<<<(N_NODES * NFP + 255) / 256, 256, 0, stream>>>(pro_x, xh1, xh32);

    // RNA branch
    k_bucket<<<BGR, 256, 0, stream>>>(rg, MAXLEN, 5, blg, bpg);
    k_bucket<<<BGR, 256, 0, stream>>>(rl, LOCLEN, 65, bll, bpl);
    k_wsum<<<dim3(BGR, 5), 256, 0, stream>>>(blg, bpg, convr1_w, Wg, MAXLEN, 5);
    k_wsum<<<dim3(BGR, 65), 256, 0, stream>>>(bll, bpl, convr2_w, Wl, LOCLEN, 65);
    k_y<<<dim3(BGR * NF, 2), 128, 0, stream>>>(Wg, Wl, emb1, emb2, convr1_b, convr2_b, yg, yl);
    k_fcpart<<<dim3(BGR, 2, NKC), 128, 0, stream>>>(yg, yl, fcxr_w, fcpart);
    k_fcred<<<BGR, 128, 0, stream>>>(fcpart, fcxr_b, out);

    // GNN stack: fused edge-parallel layers
    k_layer1<<<NBIN, 512, 0, stream>>>(xh1, xh32, binoff, er, g1_ew, g1_eb, g1_eps,
                                       g1_w1, g1_b1, g1_w2, g1_b2, zhA, bpart);
    k_bnred<<<1, 1024, 0, stream>>>(bpart, bnstat);
    __half* zi = zhA; __half* zo = zhB;
    for (int i = 0; i < 4; i++) {
        k_layer16<<<NBIN, 512, 0, stream>>>(zi, binoff, er,
                                            g_ew + i * DIM, g_eb + i * DIM, g_eps + i,
                                            bnstat + i * 32, bn_gamma + i * DIM,
                                            bn_beta + i * DIM,
                                            g_w1 + i * DIM * DIM, g_b1 + i * DIM,
                                            g_w2 + i * DIM * DIM, g_b2 + i * DIM,
                                            zo, bpart);
        k_bnred<<<1, 1024, 0, stream>>>(bpart, bnstat + (i + 1) * 32);
        __half* tmp = zi; zi = zo; zo = tmp;
    }
    k_pool<<<POOL_BLKS, 256, 0, stream>>>(zi, batch, bnstat + 4 * 32,
                                          bn_gamma + 4 * DIM, bn_beta + 4 * DIM, gsum, gcnt);
    k_xp<<<BGR, EMB, 0, stream>>>(gsum, gcnt, fc1_xp_w, fc1_xp_b, out + BGR * EMB);
}

// Round 17
// 944.418 us; speedup vs baseline: 3.3665x; 3.3665x over previous
//
#include <hip/hip_runtime.h>
#include <hip/hip_fp16.h>

#define N_NODES 100000
#define N_EDGES 3200000
#define BGR 64
#define DIM 16
#define NFP 33
#define ROW1 32
#define H1STR 36
#define EMB 128
#define MAXLEN 3000
#define LOCLEN 2998
#define NF 32
#define KS 8
#define OUTT 121
#define FC_IN 3872
#define BN_EPSV 1e-5f
#define POOL_CHUNK 256
#define POOL_BLKS 391
#define NQUAD 25000
#define AGBLK 2048
#define MLPB 391
// binned CSR build
#define NBIN 391
#define BCNT_BLK 512
#define P1_CHUNK 4096
#define P1_BLOCKS 782
#define MAXBIN 9088
// fc K-split
#define NKC 32
#define KCH 121
#define WDEC (1.f / 32767.f)

// ---------------- CSR build ----------------
__global__ void __launch_bounds__(256) k_bincnt(const int* __restrict__ dst,
                                                int* __restrict__ bh) {
    __shared__ int hist[NBIN];
    int t = threadIdx.x, bid = blockIdx.x;
    for (int b = t; b < NBIN; b += 256) hist[b] = 0;
    __syncthreads();
    int e0 = bid * (N_EDGES / BCNT_BLK);
    int e1 = e0 + (N_EDGES / BCNT_BLK);
    for (int e = e0 + t; e < e1; e += 256) atomicAdd(&hist[dst[e] >> 8], 1);
    __syncthreads();
    for (int b = t; b < NBIN; b += 256) bh[b * BCNT_BLK + bid] = hist[b];
}

__global__ void __launch_bounds__(512) k_binscan(const int* __restrict__ bh,
                                                 int* __restrict__ binoff,
                                                 int* __restrict__ bincur) {
    __shared__ int sc[512];
    int t = threadIdx.x;
    int s = 0;
    if (t < NBIN) {
        const int* row = bh + t * BCNT_BLK;
        for (int k = 0; k < BCNT_BLK; k++) s += row[k];
    }
    sc[t] = s;
    __syncthreads();
    for (int off = 1; off < 512; off <<= 1) {
        int v = (t >= off) ? sc[t - off] : 0;
        __syncthreads();
        sc[t] += v;
        __syncthreads();
    }
    int excl = sc[t] - s;
    if (t <= NBIN) binoff[t] = excl;
    if (t < NBIN) bincur[t] = excl;
}

__global__ void __launch_bounds__(256) k_part1(const int* __restrict__ src,
                                               const int* __restrict__ dst,
                                               const float* __restrict__ w,
                                               int* __restrict__ bincur,
                                               int2* __restrict__ tmp_sw) {
    __shared__ int2 srec[P1_CHUNK];
    __shared__ unsigned short sbin[P1_CHUNK];
    __shared__ unsigned short sperm[P1_CHUNK];
    __shared__ int hist[NBIN];
    __shared__ int off[NBIN];
    __shared__ int cur[NBIN];
    __shared__ int base[NBIN];
    __shared__ int sc[512];
    int t = threadIdx.x;
    int g0 = blockIdx.x * P1_CHUNK;
    int cn = N_EDGES - g0; if (cn > P1_CHUNK) cn = P1_CHUNK;
    for (int b = t; b < NBIN; b += 256) hist[b] = 0;
    __syncthreads();
    for (int j = t; j < cn; j += 256) {
        int d = dst[g0 + j];
        int b = d >> 8;
        sbin[j] = (unsigned short)b;
        srec[j] = make_int2(src[g0 + j] | ((d & 255) << 20), __float_as_int(w[g0 + j]));
        atomicAdd(&hist[b], 1);
    }
    __syncthreads();
    sc[t] = (t < NBIN) ? hist[t] : 0;
    sc[256 + t] = (256 + t < NBIN) ? hist[256 + t] : 0;
    __syncthreads();
    for (int o = 1; o <= 256; o <<= 1) {
        int v0 = (t >= o) ? sc[t - o] : 0;
        int v1 = sc[256 + t - o];
        __syncthreads();
        sc[t] += v0;
        sc[256 + t] += v1;
        __syncthreads();
    }
    for (int b = t; b < NBIN; b += 256) {
        int e = sc[b] - hist[b];
        off[b] = e;
        cur[b] = e;
        int c = hist[b];
        base[b] = c ? atomicAdd(&bincur[b], c) : 0;
    }
    __syncthreads();
    for (int j = t; j < cn; j += 256) {
        int p = atomicAdd(&cur[sbin[j]], 1);
        sperm[p] = (unsigned short)j;
    }
    __syncthreads();
    for (int p = t; p < cn; p += 256) {
        int j = sperm[p];
        int b = sbin[j];
        tmp_sw[base[b] + (p - off[b])] = srec[j];
    }
}

// pass 2: per-bin fine sort + ptr; emit compact 4B edge records src(17) | wq(15)
__global__ void __launch_bounds__(256) k_part2(const int2* __restrict__ tmp_sw,
                                               const int* __restrict__ binoff,
                                               unsigned* __restrict__ er,
                                               int* __restrict__ ptr) {
    __shared__ unsigned char sdl[MAXBIN];
    __shared__ unsigned short perm[MAXBIN];
    __shared__ int hist[256];
    __shared__ int cur[256];
    __shared__ int sc[256];
    int t = threadIdx.x, b = blockIdx.x;
    int nlo = b << 8;
    int e0 = binoff[b], e1 = binoff[b + 1];
    int cnt = e1 - e0;
    int stage = cnt < MAXBIN ? cnt : MAXBIN;
    hist[t] = 0;
    __syncthreads();
    for (int j = t; j < stage; j += 256) {
        unsigned char dl = (unsigned char)((tmp_sw[e0 + j].x >> 20) & 255);
        sdl[j] = dl;
        atomicAdd(&hist[dl], 1);
    }
    for (int j = stage + t; j < cnt; j += 256)
        atomicAdd(&hist[(tmp_sw[e0 + j].x >> 20) & 255], 1);
    __syncthreads();
    int v = hist[t];
    sc[t] = v;
    __syncthreads();
    for (int off = 1; off < 256; off <<= 1) {
        int u = (t >= off) ? sc[t - off] : 0;
        __syncthreads();
        sc[t] += u;
        __syncthreads();
    }
    int excl = sc[t] - v;
    cur[t] = excl;
    if (nlo + t < N_NODES) ptr[nlo + t] = e0 + excl;
    if (b == NBIN - 1 && t == 0) ptr[N_NODES] = N_EDGES;
    __syncthreads();
    for (int j = t; j < stage; j += 256) {
        int p = atomicAdd(&cur[sdl[j]], 1);
        perm[p] = (unsigned short)j;
    }
    __syncthreads();
    for (int j = stage + t; j < cnt; j += 256) {
        int2 sw = tmp_sw[e0 + j];
        int p = atomicAdd(&cur[(sw.x >> 20) & 255], 1);
        unsigned wq = (unsigned)(__int_as_float(sw.y) * 32767.f + 0.5f);
        er[e0 + p] = ((unsigned)sw.x & 0x1FFFFu) | (wq << 17);
    }
    for (int p = t; p < stage; p += 256) {
        int2 sw = tmp_sw[e0 + perm[p]];
        unsigned wq = (unsigned)(__int_as_float(sw.y) * 32767.f + 0.5f);
        er[e0 + p] = ((unsigned)sw.x & 0x1FFFFu) | (wq << 17);
    }
}

// ---------------- fp16 conversion of pro_x ----------------
__global__ void k_half1(const float* __restrict__ x, __half* __restrict__ xh,
                        __half* __restrict__ xh32) {
    int i = blockIdx.x * blockDim.x + threadIdx.x;
    if (i < N_NODES * NFP) {
        int n = i / NFP, f = i - n * NFP;
        __half v = __float2half(x[i]);
        if (f < 32) xh[n * ROW1 + f] = v;
        else xh32[n] = v;
    }
}

// ---------------- layer-1 aggregate (33 feats), single-node ----------------
__global__ void __launch_bounds__(256) k_agg1(
    const __half* __restrict__ xh, const __half* __restrict__ xh32,
    const int* __restrict__ ptr, const unsigned* __restrict__ er,
    const float* __restrict__ ew, const float* __restrict__ ebv,
    const float* __restrict__ epsp, float* __restrict__ h) {
    int t = threadIdx.x;
    int wave = t >> 6, lane = t & 63;
    int slot = lane >> 2, q = lane & 3;
    float4 ewa = ((const float4*)ew)[q * 2];
    float4 ewb = ((const float4*)ew)[q * 2 + 1];
    float4 eba = ((const float4*)ebv)[q * 2];
    float4 ebb = ((const float4*)ebv)[q * 2 + 1];
    float ew32 = ew[32], eb32 = ebv[32];
    float ep = 1.f + epsp[0];
    for (int quad = blockIdx.x; quad < NQUAD; quad += AGBLK) {
        int node = quad * 4 + wave;
        float a[8] = {0, 0, 0, 0, 0, 0, 0, 0};
        float a32 = 0.f;
        int e0 = ptr[node], e1 = ptr[node + 1];
        for (int i = e0 + slot; i < e1; i += 16) {
            unsigned ev = er[i];
            int s = ev & 0x1FFFF;
            float wv = (float)(ev >> 17) * WDEC;
            uint4 raw = *(const uint4*)(xh + s * ROW1 + q * 8);
            float2 f01 = __half22float2(*(__half2*)&raw.x);
            float2 f23 = __half22float2(*(__half2*)&raw.y);
            float2 f45 = __half22float2(*(__half2*)&raw.z);
            float2 f67 = __half22float2(*(__half2*)&raw.w);
            a[0] += fmaxf(f01.x + wv * ewa.x + eba.x, 0.f);
            a[1] += fmaxf(f01.y + wv * ewa.y + eba.y, 0.f);
            a[2] += fmaxf(f23.x + wv * ewa.z + eba.z, 0.f);
            a[3] += fmaxf(f23.y + wv * ewa.w + eba.w, 0.f);
            a[4] += fmaxf(f45.x + wv * ewb.x + ebb.x, 0.f);
            a[5] += fmaxf(f45.y + wv * ewb.y + ebb.y, 0.f);
            a[6] += fmaxf(f67.x + wv * ewb.z + ebb.z, 0.f);
            a[7] += fmaxf(f67.y + wv * ewb.w + ebb.w, 0.f);
            if (q == 0) a32 += fmaxf(__half2float(xh32[s]) + wv * ew32 + eb32, 0.f);
        }
        #pragma unroll
        for (int m = 4; m <= 32; m <<= 1) {
            #pragma unroll
            for (int j = 0; j < 8; j++) a[j] += __shfl_xor(a[j], m);
            a32 += __shfl_xor(a32, m);
        }
        if (slot == 0) {
            uint4 sraw = *(const uint4*)(xh + node * ROW1 + q * 8);
            float2 s01 = __half22float2(*(__half2*)&sraw.x);
            float2 s23 = __half22float2(*(__half2*)&sraw.y);
            float2 s45 = __half22float2(*(__half2*)&sraw.z);
            float2 s67 = __half22float2(*(__half2*)&sraw.w);
            float* hp = h + node * H1STR + q * 8;
            *(float4*)hp = make_float4(ep * s01.x + a[0], ep * s01.y + a[1],
                                       ep * s23.x + a[2], ep * s23.y + a[3]);
            *(float4*)(hp + 4) = make_float4(ep * s45.x + a[4], ep * s45.y + a[5],
                                             ep * s67.x + a[6], ep * s67.y + a[7]);
            if (q == 0)
                h[node * H1STR + 32] = ep * __half2float(xh32[node]) + a32;
        }
    }
}

// ---------------- layer 2-5 aggregate (16 feats), BN folded, dual-node ----------------
__global__ void __launch_bounds__(256) k_agg16(
    const __half* __restrict__ zh, const int* __restrict__ ptr,
    const unsigned* __restrict__ er,
    const float* __restrict__ ew, const float* __restrict__ ebv,
    const float* __restrict__ epsp,
    const float* __restrict__ bnstat, const float* __restrict__ gamma,
    const float* __restrict__ beta, float* __restrict__ h) {
    int t = threadIdx.x;
    int wave = t >> 6, lane = t & 63;
    int slot = lane >> 1, hh = lane & 1;
    float ep = 1.f + epsp[0];
    const float invn = 1.f / (float)N_NODES;
    float scf[8], shf[8], cbf[8], ewf[8];
    #pragma unroll
    for (int j = 0; j < 8; j++) {
        int f = hh * 8 + j;
        float mu = bnstat[f] * invn;
        float var = bnstat[DIM + f] * invn - mu * mu;
        float sc = gamma[f] * rsqrtf(var + BN_EPSV);
        scf[j] = sc;
        shf[j] = beta[f] - mu * sc;
        cbf[j] = shf[j] + ebv[f];
        ewf[j] = ew[f];
    }
    for (int quad = blockIdx.x; quad < NQUAD; quad += 2 * AGBLK) {
        int quadB = quad + AGBLK;
        bool hasB = quadB < NQUAD;
        int nodeA = quad * 4 + wave;
        int nodeB = hasB ? quadB * 4 + wave : nodeA;
        float a[8] = {0, 0, 0, 0, 0, 0, 0, 0};
        float b[8] = {0, 0, 0, 0, 0, 0, 0, 0};
        int e0a = ptr[nodeA], e1a = ptr[nodeA + 1];
        int e0b = ptr[nodeB], e1b = ptr[nodeB + 1];
        if (!hasB) e1b = e0b;
        int ia = e0a + slot, ib = e0b + slot;
        while (ia < e1a || ib < e1b) {
            bool da = ia < e1a, db = ib < e1b;
            unsigned evA = 0, evB = 0;
            if (da) evA = er[ia];
            if (db) evB = er[ib];
            uint4 rA, rB;
            float wvA = 0.f, wvB = 0.f;
            if (da) {
                rA = *(const uint4*)(zh + (evA & 0x1FFFF) * DIM + hh * 8);
                wvA = (float)(evA >> 17) * WDEC;
            }
            if (db) {
                rB = *(const uint4*)(zh + (evB & 0x1FFFF) * DIM + hh * 8);
                wvB = (float)(evB >> 17) * WDEC;
            }
            if (da) {
                float2 f01 = __half22float2(*(__half2*)&rA.x);
                float2 f23 = __half22float2(*(__half2*)&rA.y);
                float2 f45 = __half22float2(*(__half2*)&rA.z);
                float2 f67 = __half22float2(*(__half2*)&rA.w);
                float x[8] = {f01.x, f01.y, f23.x, f23.y, f45.x, f45.y, f67.x, f67.y};
                #pragma unroll
                for (int j = 0; j < 8; j++) {
                    float tb = fmaf(wvA, ewf[j], cbf[j]);
                    a[j] += fmaxf(fmaf(x[j], scf[j], tb), 0.f);
                }
            }
            if (db) {
                float2 f01 = __half22float2(*(__half2*)&rB.x);
                float2 f23 = __half22float2(*(__half2*)&rB.y);
                float2 f45 = __half22float2(*(__half2*)&rB.z);
                float2 f67 = __half22float2(*(__half2*)&rB.w);
                float x[8] = {f01.x, f01.y, f23.x, f23.y, f45.x, f45.y, f67.x, f67.y};
                #pragma unroll
                for (int j = 0; j < 8; j++) {
                    float tb = fmaf(wvB, ewf[j], cbf[j]);
                    b[j] += fmaxf(fmaf(x[j], scf[j], tb), 0.f);
                }
            }
            ia += 32; ib += 32;
        }
        #pragma unroll
        for (int m = 2; m <= 32; m <<= 1) {
            #pragma unroll
            for (int j = 0; j < 8; j++) {
                a[j] += __shfl_xor(a[j], m);
                b[j] += __shfl_xor(b[j], m);
            }
        }
        if (lane < 2) {
            {
                uint4 sraw = *(const uint4*)(zh + nodeA * DIM + lane * 8);
                float2 s01 = __half22float2(*(__half2*)&sraw.x);
                float2 s23 = __half22float2(*(__half2*)&sraw.y);
                float2 s45 = __half22float2(*(__half2*)&sraw.z);
                float2 s67 = __half22float2(*(__half2*)&sraw.w);
                float xs[8] = {s01.x, s01.y, s23.x, s23.y, s45.x, s45.y, s67.x, s67.y};
                float o8[8];
                #pragma unroll
                for (int j = 0; j < 8; j++)
                    o8[j] = ep * fmaf(xs[j], scf[j], shf[j]) + a[j];
                float* hp = h + nodeA * DIM + lane * 8;
                *(float4*)hp = make_float4(o8[0], o8[1], o8[2], o8[3]);
                *(float4*)(hp + 4) = make_float4(o8[4], o8[5], o8[6], o8[7]);
            }
            if (hasB) {
                uint4 sraw = *(const uint4*)(zh + nodeB * DIM + lane * 8);
                float2 s01 = __half22float2(*(__half2*)&sraw.x);
                float2 s23 = __half22float2(*(__half2*)&sraw.y);
                float2 s45 = __half22float2(*(__half2*)&sraw.z);
                float2 s67 = __half22float2(*(__half2*)&sraw.w);
                float xs[8] = {s01.x, s01.y, s23.x, s23.y, s45.x, s45.y, s67.x, s67.y};
                float o8[8];
                #pragma unroll
                for (int j = 0; j < 8; j++)
                    o8[j] = ep * fmaf(xs[j], scf[j], shf[j]) + b[j];
                float* hp = h + nodeB * DIM + lane * 8;
                *(float4*)hp = make_float4(o8[0], o8[1], o8[2], o8[3]);
                *(float4*)(hp + 4) = make_float4(o8[4], o8[5], o8[6], o8[7]);
            }
        }
    }
}

// ---------------- fused MLP + BN partials + last-block bnstat reduction ----------------
__device__ __forceinline__ void mlp_bn_tail(float zv[16], bool active, int t,
                                            float* __restrict__ part,
                                            int* __restrict__ cnt,
                                            float* __restrict__ bnstat) {
    __shared__ float red[4][32];
    __shared__ float red2[256];
    __shared__ int lastflag;
    float zs[16], zq[16];
    #pragma unroll
    for (int o = 0; o < 16; o++) {
        zs[o] = active ? zv[o] : 0.f;
        zq[o] = active ? zv[o] * zv[o] : 0.f;
    }
    #pragma unroll
    for (int m = 1; m <= 32; m <<= 1) {
        #pragma unroll
        for (int o = 0; o < 16; o++) {
            zs[o] += __shfl_xor(zs[o], m);
            zq[o] += __shfl_xor(zq[o], m);
        }
    }
    int wave = t >> 6, lane = t & 63;
    if (lane == 0) {
        #pragma unroll
        for (int o = 0; o < 16; o++) {
            red[wave][o] = zs[o];
            red[wave][16 + o] = zq[o];
        }
    }
    __syncthreads();
    if (t < 32)
        part[blockIdx.x * 32 + t] = red[0][t] + red[1][t] + red[2][t] + red[3][t];
    __threadfence();
    if (t == 0) lastflag = (atomicAdd(cnt, 1) == MLPB - 1) ? 1 : 0;
    __syncthreads();
    if (lastflag) {
        __threadfence();
        int f = t & 31, g = t >> 5;
        float s = 0.f;
        for (int i = g; i < MLPB; i += 8) s += part[i * 32 + f];
        red2[t] = s;
        __syncthreads();
        for (int off = 128; off >= 32; off >>= 1) {
            if (t < off) red2[t] += red2[t + off];
            __syncthreads();
        }
        if (t < 32) bnstat[t] = red2[t];
    }
}

__device__ __forceinline__ void store_zh(__half* __restrict__ zh, int n, float zv[16]) {
    __half2 p[8];
    #pragma unroll
    for (int j = 0; j < 8; j++) p[j] = __floats2half2_rn(zv[2 * j], zv[2 * j + 1]);
    *(uint4*)(zh + n * DIM) = *(uint4*)&p[0];
    *(uint4*)(zh + n * DIM + 8) = *(uint4*)&p[4];
}

__global__ void __launch_bounds__(256) k_mlp16(
    const float* __restrict__ h,
    const float* __restrict__ W1, const float* __restrict__ b1,
    const float* __restrict__ W2, const float* __restrict__ b2,
    __half* __restrict__ zh, float* __restrict__ part,
    int* __restrict__ cnt, float* __restrict__ bnstat) {
    __shared__ float W1s[256], W2s[256], b1s[16], b2s[16];
    int t = threadIdx.x;
    W1s[t] = W1[t];
    W2s[t] = W2[t];
    if (t < 16) { b1s[t] = b1[t]; b2s[t] = b2[t]; }
    __syncthreads();
    int n = blockIdx.x * 256 + t;
    bool active = n < N_NODES;
    float zv[16];
    if (active) {
        float hv[16];
        #pragma unroll
        for (int j = 0; j < 4; j++) {
            float4 v = *(const float4*)(h + n * DIM + j * 4);
            hv[j * 4] = v.x; hv[j * 4 + 1] = v.y; hv[j * 4 + 2] = v.z; hv[j * 4 + 3] = v.w;
        }
        float tv[16];
        #pragma unroll
        for (int o = 0; o < 16; o++) {
            float s = b1s[o];
            #pragma unroll
            for (int f = 0; f < 16; f++) s += hv[f] * W1s[f * 16 + o];
            tv[o] = fmaxf(s, 0.f);
        }
        #pragma unroll
        for (int o = 0; o < 16; o++) {
            float s = b2s[o];
            #pragma unroll
            for (int f = 0; f < 16; f++) s += tv[f] * W2s[f * 16 + o];
            zv[o] = fmaxf(s, 0.f);
        }
        store_zh(zh, n, zv);
    }
    mlp_bn_tail(zv, active, t, part, cnt, bnstat);
}

__global__ void __launch_bounds__(256) k_mlp1(
    const float* __restrict__ h,
    const float* __restrict__ W1, const float* __restrict__ b1,
    const float* __restrict__ W2, const float* __restrict__ b2,
    __half* __restrict__ zh, float* __restrict__ part,
    int* __restrict__ cnt, float* __restrict__ bnstat) {
    __shared__ float W1s[NFP * 16], W2s[256], b1s[16], b2s[16];
    int t = threadIdx.x;
    for (int j = t; j < NFP * 16; j += 256) W1s[j] = W1[j];
    W2s[t] = W2[t];
    if (t < 16) { b1s[t] = b1[t]; b2s[t] = b2[t]; }
    __syncthreads();
    int n = blockIdx.x * 256 + t;
    bool active = n < N_NODES;
    float zv[16];
    if (active) {
        float hv[NFP];
        #pragma unroll
        for (int j = 0; j < 8; j++) {
            float4 v = *(const float4*)(h + n * H1STR + j * 4);
            hv[j * 4] = v.x; hv[j * 4 + 1] = v.y; hv[j * 4 + 2] = v.z; hv[j * 4 + 3] = v.w;
        }
        hv[32] = h[n * H1STR + 32];
        float tv[16];
        #pragma unroll
        for (int o = 0; o < 16; o++) {
            float s = b1s[o];
            #pragma unroll
            for (int f = 0; f < NFP; f++) s += hv[f] * W1s[f * 16 + o];
            tv[o] = fmaxf(s, 0.f);
        }
        #pragma unroll
        for (int o = 0; o < 16; o++) {
            float s = b2s[o];
            #pragma unroll
            for (int f = 0; f < 16; f++) s += tv[f] * W2s[f * 16 + o];
            zv[o] = fmaxf(s, 0.f);
        }
        store_zh(zh, n, zv);
    }
    mlp_bn_tail(zv, active, t, part, cnt, bnstat);
}

// ---------------- pooling with BN folded + last-block fc1_xp ----------------
__global__ void __launch_bounds__(256) k_pool(const __half* __restrict__ zh,
                                              const int* __restrict__ batch,
                                              const float* __restrict__ bnstat,
                                              const float* __restrict__ gamma,
                                              const float* __restrict__ beta,
                                              float* __restrict__ gsum,
                                              float* __restrict__ gcnt,
                                              int* __restrict__ cnt,
                                              const float* __restrict__ xpw,
                                              const float* __restrict__ xpb,
                                              float* __restrict__ out) {
    __shared__ float lsum[BGR * DIM];
    __shared__ float lcnt[BGR];
    __shared__ int lastflag;
    int t = threadIdx.x;
    for (int j = t; j < BGR * DIM; j += 256) lsum[j] = 0.f;
    if (t < BGR) lcnt[t] = 0.f;
    __syncthreads();
    int f = t & 15, r = t >> 4;
    const float invn = 1.f / (float)N_NODES;
    float mu = bnstat[f] * invn;
    float var = bnstat[DIM + f] * invn - mu * mu;
    float sc = gamma[f] * rsqrtf(var + BN_EPSV);
    float sh = beta[f] - mu * sc;
    int start = blockIdx.x * POOL_CHUNK;
    float acc = 0.f, cacc = 0.f;
    int cur = -1;
    for (int i = 0; i < POOL_CHUNK / 16; i++) {
        int n = start + r + i * 16;
        if (n >= N_NODES) break;
        int b = batch[n];
        if (b != cur) {
            if (cur >= 0) {
                atomicAdd(&lsum[cur * DIM + f], acc);
                if (f == 0) atomicAdd(&lcnt[cur], cacc);
            }
            cur = b; acc = 0.f; cacc = 0.f;
        }
        acc += fmaf(__half2float(zh[n * DIM + f]), sc, sh);
        cacc += 1.f;
    }
    if (cur >= 0) {
        atomicAdd(&lsum[cur * DIM + f], acc);
        if (f == 0) atomicAdd(&lcnt[cur], cacc);
    }
    __syncthreads();
    for (int j = t; j < BGR * DIM; j += 256) {
        float v = lsum[j];
        if (v != 0.f) atomicAdd(&gsum[j], v);
    }
    if (t < BGR) {
        float v = lcnt[t];
        if (v != 0.f) atomicAdd(&gcnt[t], v);
    }
    __threadfence();
    if (t == 0) lastflag = (atomicAdd(cnt, 1) == POOL_BLKS - 1) ? 1 : 0;
    __syncthreads();
    if (lastflag) {
        __threadfence();
        for (int idx = t; idx < BGR * EMB; idx += 256) {
            int b = idx >> 7, e = idx & 127;
            float inv = 1.f / fmaxf(gcnt[b], 1.f);
            float a2 = xpb[e];
            #pragma unroll
            for (int ff = 0; ff < DIM; ff++) a2 += gsum[b * DIM + ff] * inv * xpw[ff * EMB + e];
            out[idx] = fmaxf(a2, 0.f);
        }
    }
}

// ---------------- RNA ----------------
__global__ void __launch_bounds__(256) k_bucket(const int* __restrict__ tok, int L, int V,
                                                int* __restrict__ blist,
                                                int* __restrict__ bptr) {
    __shared__ int hist[65];
    __shared__ int cursor[65];
    int b = blockIdx.x, t = threadIdx.x;
    if (t < V) hist[t] = 0;
    __syncthreads();
    for (int l = t; l < L; l += 256) atomicAdd(&hist[tok[b * L + l]], 1);
    __syncthreads();
    if (t == 0) {
        int run = 0;
        for (int v = 0; v < V; v++) {
            cursor[v] = run;
            bptr[b * (V + 1) + v] = run;
            run += hist[v];
        }
        bptr[b * (V + 1) + V] = run;
    }
    __syncthreads();
    for (int l = t; l < L; l += 256) {
        int v = tok[b * L + l];
        int p = atomicAdd(&cursor[v], 1);
        blist[b * L + p] = l;
    }
}

__global__ void __launch_bounds__(256) k_wsum(const int* __restrict__ blist,
                                              const int* __restrict__ bptr,
                                              const float* __restrict__ cw,
                                              float* __restrict__ W, int L, int V) {
    int b = blockIdx.x, v = blockIdx.y;
    int t = threadIdx.x, o = t >> 3, k = t & 7;
    int s = bptr[b * (V + 1) + v], e = bptr[b * (V + 1) + v + 1];
    __shared__ int tk[256];
    const float* cwp = cw + o * (L * KS) + k;
    float acc = 0.f;
    for (int j0 = s; j0 < e; j0 += 256) {
        int lim = e - j0; if (lim > 256) lim = 256;
        __syncthreads();
        if (t < lim) tk[t] = blist[b * L + j0 + t];
        __syncthreads();
        for (int j = 0; j < lim; j++) acc += cwp[tk[j] * KS];
    }
    W[((b * NF + o) * V + v) * KS + k] = acc;
}

__global__ void k_y(const float* __restrict__ Wg, const float* __restrict__ Wl,
                    const float* __restrict__ emb1, const float* __restrict__ emb2,
                    const float* __restrict__ cb1, const float* __restrict__ cb2,
                    float* __restrict__ yg, float* __restrict__ yl) {
    int which = blockIdx.y;
    int bo = blockIdx.x;
    int b = bo >> 5, o = bo & 31;
    int t = threadIdx.x;  // 128
    const float* W = which ? Wl : Wg;
    const float* emb = which ? emb2 : emb1;
    const float* cb = which ? cb2 : cb1;
    float* y = which ? yl : yg;
    int V = which ? 65 : 5;
    __shared__ float Wsh[65 * KS];
    const float* Wrow = W + (b * NF + o) * V * KS;
    for (int j = t; j < V * KS; j += 128) Wsh[j] = Wrow[j];
    __syncthreads();
    if (t < OUTT) {
        float acc = cb[o];
        for (int v = 0; v < V; v++) {
            const float* ep = emb + v * EMB + t;
            #pragma unroll
            for (int k = 0; k < KS; k++) acc += Wsh[v * KS + k] * ep[k];
        }
        y[(b * NF + o) * OUTT + t] = acc;
    }
}

__global__ void __launch_bounds__(128) k_fcpart(const float* __restrict__ yg,
                                                const float* __restrict__ yl,
                                                const float* __restrict__ w,
                                                float* __restrict__ partial) {
    int b = blockIdx.x, which = blockIdx.y, kc = blockIdx.z;
    const float* y = which ? yl : yg;
    int e = threadIdx.x;
    __shared__ float ych[KCH];
    int j0 = kc * KCH;
    if (e < KCH) ych[e] = y[b * FC_IN + j0 + e];
    __syncthreads();
    float acc = 0.f;
    #pragma unroll 4
    for (int jj = 0; jj < KCH; jj++) acc += ych[jj] * w[(j0 + jj) * EMB + e];
    partial[((which * BGR + b) * NKC + kc) * EMB + e] = acc;
}

__global__ void k_fcred(const float* __restrict__ partial, const float* __restrict__ bias,
                        float* __restrict__ out) {
    int b = blockIdx.x;
    int e = threadIdx.x;
    const float* pg = partial + b * NKC * EMB + e;
    const float* pl = partial + (BGR + b) * NKC * EMB + e;
    float ag = bias[e], al = bias[e];
    #pragma unroll
    for (int k = 0; k < NKC; k++) { ag += pg[k * EMB]; al += pl[k * EMB]; }
    out[b * EMB + e] = 0.5f * (ag + al);
}

extern "C" void kernel_launch(void* const* d_in, const int* in_sizes, int n_in,
                              void* d_out, int out_size, void* d_ws, size_t ws_size,
                              hipStream_t stream) {
    const float* pro_x = (const float*)d_in[0];
    const int* eidx = (const int*)d_in[1];
    const int* esrc = eidx;
    const int* edst = eidx + N_EDGES;
    const float* pw = (const float*)d_in[2];
    const int* batch = (const int*)d_in[3];
    const int* rg = (const int*)d_in[4];
    const int* rl = (const int*)d_in[5];
    const float* g1_w1 = (const float*)d_in[6];
    const float* g1_b1 = (const float*)d_in[7];
    const float* g1_w2 = (const float*)d_in[8];
    const float* g1_b2 = (const float*)d_in[9];
    const float* g1_ew = (const float*)d_in[10];
    const float* g1_eb = (const float*)d_in[11];
    const float* g1_eps = (const float*)d_in[12];
    const float* g_w1 = (const float*)d_in[13];
    const float* g_b1 = (const float*)d_in[14];
    const float* g_w2 = (const float*)d_in[15];
    const float* g_b2 = (const float*)d_in[16];
    const float* g_ew = (const float*)d_in[17];
    const float* g_eb = (const float*)d_in[18];
    const float* g_eps = (const float*)d_in[19];
    const float* bn_gamma = (const float*)d_in[20];
    const float* bn_beta = (const float*)d_in[21];
    const float* fc1_xp_w = (const float*)d_in[22];
    const float* fc1_xp_b = (const float*)d_in[23];
    const float* emb1 = (const float*)d_in[24];
    const float* emb2 = (const float*)d_in[25];
    const float* convr1_w = (const float*)d_in[26];
    const float* convr1_b = (const float*)d_in[27];
    const float* convr2_w = (const float*)d_in[28];
    const float* convr2_b = (const float*)d_in[29];
    const float* fcxr_w = (const float*)d_in[30];
    const float* fcxr_b = (const float*)d_in[31];
    float* out = (float*)d_out;

    // persistent buffers
    float* wsf = (float*)d_ws;
    int* ptr       = (int*)wsf;        wsf += 100128;
    int* binoff    = (int*)wsf;        wsf += 512;
    int* bincur    = (int*)wsf;        wsf += 512;
    unsigned* er   = (unsigned*)wsf;   wsf += 2 * N_EDGES;
    float* stats   = wsf;              wsf += 1312;  // gsum[1024] gcnt[64] bnstat[192] cnts[8]+pad
    // union region
    float* un = wsf;
    int2* tmp_sw          = (int2*)un;
    int* bh               = (int*)(un + 7200000);
    __half* zh   = (__half*)(un + 1600000);
    __half* xh1  = (__half*)(un + 2400000);
    __half* xh32 = (__half*)(un + 4000000);
    float* bpart = un + 4100000;
    float* Wg    = un + 4300000;
    float* Wl    = un + 4382000;
    float* yg    = un + 5447000;
    float* yl    = un + 5695000;
    int* blg     = (int*)(un + 5961000);
    int* bll     = (int*)(un + 6153000);
    int* bpg     = (int*)(un + 6345000);
    int* bpl     = (int*)(un + 6346000);
    float* fcpart = un + 6360000;
    float* h      = un + 7400000;
    float* gsum   = stats;
    float* gcnt   = stats + 1024;
    float* bnstat = stats + 1088;
    int* cnts     = (int*)(stats + 1280);

    hipMemsetAsync(stats, 0, 1312 * sizeof(float), stream);

    // CSR build
    k_bincnt<<<BCNT_BLK, 256, 0, stream>>>(edst, bh);
    k_binscan<<<1, 512, 0, stream>>>(bh, binoff, bincur);
    k_part1<<<P1_BLOCKS, 256, 0, stream>>>(esrc, edst, pw, bincur, tmp_sw);
    k_part2<<<NBIN, 256, 0, stream>>>(tmp_sw, binoff, er, ptr);

    // pro_x -> fp16 rows
    k_half1<<<(N_NODES * NFP + 255) / 256, 256, 0, stream>>>(pro_x, xh1, xh32);

    // RNA branch
    k_bucket<<<BGR, 256, 0, stream>>>(rg, MAXLEN, 5, blg, bpg);
    k_bucket<<<BGR, 256, 0, stream>>>(rl, LOCLEN, 65, bll, bpl);
    k_wsum<<<dim3(BGR, 5), 256, 0, stream>>>(blg, bpg, convr1_w, Wg, MAXLEN, 5);
    k_wsum<<<dim3(BGR, 65), 256, 0, stream>>>(bll, bpl, convr2_w, Wl, LOCLEN, 65);
    k_y<<<dim3(BGR * NF, 2), 128, 0, stream>>>(Wg, Wl, emb1, emb2, convr1_b, convr2_b, yg, yl);
    k_fcpart<<<dim3(BGR, 2, NKC), 128, 0, stream>>>(yg, yl, fcxr_w, fcpart);
    k_fcred<<<BGR, 128, 0, stream>>>(fcpart, fcxr_b, out);

    // GNN stack (bnred fused into mlp via last-block pattern)
    k_agg1<<<AGBLK, 256, 0, stream>>>(xh1, xh32, ptr, er, g1_ew, g1_eb, g1_eps, h);
    k_mlp1<<<MLPB, 256, 0, stream>>>(h, g1_w1, g1_b1, g1_w2, g1_b2, zh, bpart,
                                     cnts + 0, bnstat);
    for (int i = 0; i < 4; i++) {
        k_agg16<<<AGBLK, 256, 0, stream>>>(zh, ptr, er,
                                           g_ew + i * DIM, g_eb + i * DIM, g_eps + i,
                                           bnstat + i * 32, bn_gamma + i * DIM,
                                           bn_beta + i * DIM, h);
        k_mlp16<<<MLPB, 256, 0, stream>>>(h, g_w1 + i * DIM * DIM, g_b1 + i * DIM,
                                          g_w2 + i * DIM * DIM, g_b2 + i * DIM, zh, bpart,
                                          cnts + 1 + i, bnstat + (i + 1) * 32);
    }
    k_pool<<<POOL_BLKS, 256, 0, stream>>>(zh, batch, bnstat + 4 * 32,
                                          bn_gamma + 4 * DIM, bn_beta + 4 * DIM, gsum, gcnt,
                                          cnts + 5, fc1_xp_w, fc1_xp_b, out + BGR * EMB);
}

// Round 18
// 854.370 us; speedup vs baseline: 3.7213x; 1.1054x over previous
//
#include <hip/hip_runtime.h>
#include <hip/hip_fp16.h>

#define N_NODES 100000
#define N_EDGES 3200000
#define BGR 64
#define DIM 16
#define NFP 33
#define ROW1 32
#define H1STR 36
#define EMB 128
#define MAXLEN 3000
#define LOCLEN 2998
#define NF 32
#define KS 8
#define OUTT 121
#define FC_IN 3872
#define BN_EPSV 1e-5f
#define POOL_CHUNK 256
#define POOL_BLKS 391
#define NQUAD 25000
#define AGBLK 2048
#define MLPB 391
// binned CSR build
#define NBIN 391
#define BCNT_BLK 512
#define P1_CHUNK 4096
#define P1_BLOCKS 782
#define MAXBIN 9088
// fc K-split
#define NKC 32
#define KCH 121
#define WDEC (1.f / 32767.f)

// ---------------- CSR build ----------------
__global__ void __launch_bounds__(256) k_bincnt(const int* __restrict__ dst,
                                                int* __restrict__ bh) {
    __shared__ int hist[NBIN];
    int t = threadIdx.x, bid = blockIdx.x;
    for (int b = t; b < NBIN; b += 256) hist[b] = 0;
    __syncthreads();
    int e0 = bid * (N_EDGES / BCNT_BLK);
    int e1 = e0 + (N_EDGES / BCNT_BLK);
    for (int e = e0 + t; e < e1; e += 256) atomicAdd(&hist[dst[e] >> 8], 1);
    __syncthreads();
    for (int b = t; b < NBIN; b += 256) bh[b * BCNT_BLK + bid] = hist[b];
}

__global__ void __launch_bounds__(512) k_binscan(const int* __restrict__ bh,
                                                 int* __restrict__ binoff,
                                                 int* __restrict__ bincur) {
    __shared__ int sc[512];
    int t = threadIdx.x;
    int s = 0;
    if (t < NBIN) {
        const int* row = bh + t * BCNT_BLK;
        for (int k = 0; k < BCNT_BLK; k++) s += row[k];
    }
    sc[t] = s;
    __syncthreads();
    for (int off = 1; off < 512; off <<= 1) {
        int v = (t >= off) ? sc[t - off] : 0;
        __syncthreads();
        sc[t] += v;
        __syncthreads();
    }
    int excl = sc[t] - s;
    if (t <= NBIN) binoff[t] = excl;
    if (t < NBIN) bincur[t] = excl;
}

__global__ void __launch_bounds__(256) k_part1(const int* __restrict__ src,
                                               const int* __restrict__ dst,
                                               const float* __restrict__ w,
                                               int* __restrict__ bincur,
                                               int2* __restrict__ tmp_sw) {
    __shared__ int2 srec[P1_CHUNK];
    __shared__ unsigned short sbin[P1_CHUNK];
    __shared__ unsigned short sperm[P1_CHUNK];
    __shared__ int hist[NBIN];
    __shared__ int off[NBIN];
    __shared__ int cur[NBIN];
    __shared__ int base[NBIN];
    __shared__ int sc[512];
    int t = threadIdx.x;
    int g0 = blockIdx.x * P1_CHUNK;
    int cn = N_EDGES - g0; if (cn > P1_CHUNK) cn = P1_CHUNK;
    for (int b = t; b < NBIN; b += 256) hist[b] = 0;
    __syncthreads();
    for (int j = t; j < cn; j += 256) {
        int d = dst[g0 + j];
        int b = d >> 8;
        sbin[j] = (unsigned short)b;
        srec[j] = make_int2(src[g0 + j] | ((d & 255) << 20), __float_as_int(w[g0 + j]));
        atomicAdd(&hist[b], 1);
    }
    __syncthreads();
    sc[t] = (t < NBIN) ? hist[t] : 0;
    sc[256 + t] = (256 + t < NBIN) ? hist[256 + t] : 0;
    __syncthreads();
    for (int o = 1; o <= 256; o <<= 1) {
        int v0 = (t >= o) ? sc[t - o] : 0;
        int v1 = sc[256 + t - o];
        __syncthreads();
        sc[t] += v0;
        sc[256 + t] += v1;
        __syncthreads();
    }
    for (int b = t; b < NBIN; b += 256) {
        int e = sc[b] - hist[b];
        off[b] = e;
        cur[b] = e;
        int c = hist[b];
        base[b] = c ? atomicAdd(&bincur[b], c) : 0;
    }
    __syncthreads();
    for (int j = t; j < cn; j += 256) {
        int p = atomicAdd(&cur[sbin[j]], 1);
        sperm[p] = (unsigned short)j;
    }
    __syncthreads();
    for (int p = t; p < cn; p += 256) {
        int j = sperm[p];
        int b = sbin[j];
        tmp_sw[base[b] + (p - off[b])] = srec[j];
    }
}

// pass 2: per-bin fine sort + ptr; emit compact 4B edge records src(17) | wq(15)
__global__ void __launch_bounds__(256) k_part2(const int2* __restrict__ tmp_sw,
                                               const int* __restrict__ binoff,
                                               unsigned* __restrict__ er,
                                               int* __restrict__ ptr) {
    __shared__ unsigned char sdl[MAXBIN];
    __shared__ unsigned short perm[MAXBIN];
    __shared__ int hist[256];
    __shared__ int cur[256];
    __shared__ int sc[256];
    int t = threadIdx.x, b = blockIdx.x;
    int nlo = b << 8;
    int e0 = binoff[b], e1 = binoff[b + 1];
    int cnt = e1 - e0;
    int stage = cnt < MAXBIN ? cnt : MAXBIN;
    hist[t] = 0;
    __syncthreads();
    for (int j = t; j < stage; j += 256) {
        unsigned char dl = (unsigned char)((tmp_sw[e0 + j].x >> 20) & 255);
        sdl[j] = dl;
        atomicAdd(&hist[dl], 1);
    }
    for (int j = stage + t; j < cnt; j += 256)
        atomicAdd(&hist[(tmp_sw[e0 + j].x >> 20) & 255], 1);
    __syncthreads();
    int v = hist[t];
    sc[t] = v;
    __syncthreads();
    for (int off = 1; off < 256; off <<= 1) {
        int u = (t >= off) ? sc[t - off] : 0;
        __syncthreads();
        sc[t] += u;
        __syncthreads();
    }
    int excl = sc[t] - v;
    cur[t] = excl;
    if (nlo + t < N_NODES) ptr[nlo + t] = e0 + excl;
    if (b == NBIN - 1 && t == 0) ptr[N_NODES] = N_EDGES;
    __syncthreads();
    for (int j = t; j < stage; j += 256) {
        int p = atomicAdd(&cur[sdl[j]], 1);
        perm[p] = (unsigned short)j;
    }
    __syncthreads();
    for (int j = stage + t; j < cnt; j += 256) {
        int2 sw = tmp_sw[e0 + j];
        int p = atomicAdd(&cur[(sw.x >> 20) & 255], 1);
        unsigned wq = (unsigned)(__int_as_float(sw.y) * 32767.f + 0.5f);
        er[e0 + p] = ((unsigned)sw.x & 0x1FFFFu) | (wq << 17);
    }
    for (int p = t; p < stage; p += 256) {
        int2 sw = tmp_sw[e0 + perm[p]];
        unsigned wq = (unsigned)(__int_as_float(sw.y) * 32767.f + 0.5f);
        er[e0 + p] = ((unsigned)sw.x & 0x1FFFFu) | (wq << 17);
    }
}

// ---------------- fp16 conversion of pro_x ----------------
__global__ void k_half1(const float* __restrict__ x, __half* __restrict__ xh,
                        __half* __restrict__ xh32) {
    int i = blockIdx.x * blockDim.x + threadIdx.x;
    if (i < N_NODES * NFP) {
        int n = i / NFP, f = i - n * NFP;
        __half v = __float2half(x[i]);
        if (f < 32) xh[n * ROW1 + f] = v;
        else xh32[n] = v;
    }
}

// ---------------- layer-1 aggregate (33 feats), single-node ----------------
__global__ void __launch_bounds__(256) k_agg1(
    const __half* __restrict__ xh, const __half* __restrict__ xh32,
    const int* __restrict__ ptr, const unsigned* __restrict__ er,
    const float* __restrict__ ew, const float* __restrict__ ebv,
    const float* __restrict__ epsp, float* __restrict__ h) {
    int t = threadIdx.x;
    int wave = t >> 6, lane = t & 63;
    int slot = lane >> 2, q = lane & 3;
    float4 ewa = ((const float4*)ew)[q * 2];
    float4 ewb = ((const float4*)ew)[q * 2 + 1];
    float4 eba = ((const float4*)ebv)[q * 2];
    float4 ebb = ((const float4*)ebv)[q * 2 + 1];
    float ew32 = ew[32], eb32 = ebv[32];
    float ep = 1.f + epsp[0];
    for (int quad = blockIdx.x; quad < NQUAD; quad += AGBLK) {
        int node = quad * 4 + wave;
        float a[8] = {0, 0, 0, 0, 0, 0, 0, 0};
        float a32 = 0.f;
        int e0 = ptr[node], e1 = ptr[node + 1];
        for (int i = e0 + slot; i < e1; i += 16) {
            unsigned ev = er[i];
            int s = ev & 0x1FFFF;
            float wv = (float)(ev >> 17) * WDEC;
            uint4 raw = *(const uint4*)(xh + s * ROW1 + q * 8);
            float2 f01 = __half22float2(*(__half2*)&raw.x);
            float2 f23 = __half22float2(*(__half2*)&raw.y);
            float2 f45 = __half22float2(*(__half2*)&raw.z);
            float2 f67 = __half22float2(*(__half2*)&raw.w);
            a[0] += fmaxf(f01.x + wv * ewa.x + eba.x, 0.f);
            a[1] += fmaxf(f01.y + wv * ewa.y + eba.y, 0.f);
            a[2] += fmaxf(f23.x + wv * ewa.z + eba.z, 0.f);
            a[3] += fmaxf(f23.y + wv * ewa.w + eba.w, 0.f);
            a[4] += fmaxf(f45.x + wv * ewb.x + ebb.x, 0.f);
            a[5] += fmaxf(f45.y + wv * ewb.y + ebb.y, 0.f);
            a[6] += fmaxf(f67.x + wv * ewb.z + ebb.z, 0.f);
            a[7] += fmaxf(f67.y + wv * ewb.w + ebb.w, 0.f);
            if (q == 0) a32 += fmaxf(__half2float(xh32[s]) + wv * ew32 + eb32, 0.f);
        }
        #pragma unroll
        for (int m = 4; m <= 32; m <<= 1) {
            #pragma unroll
            for (int j = 0; j < 8; j++) a[j] += __shfl_xor(a[j], m);
            a32 += __shfl_xor(a32, m);
        }
        if (slot == 0) {
            uint4 sraw = *(const uint4*)(xh + node * ROW1 + q * 8);
            float2 s01 = __half22float2(*(__half2*)&sraw.x);
            float2 s23 = __half22float2(*(__half2*)&sraw.y);
            float2 s45 = __half22float2(*(__half2*)&sraw.z);
            float2 s67 = __half22float2(*(__half2*)&sraw.w);
            float* hp = h + node * H1STR + q * 8;
            *(float4*)hp = make_float4(ep * s01.x + a[0], ep * s01.y + a[1],
                                       ep * s23.x + a[2], ep * s23.y + a[3]);
            *(float4*)(hp + 4) = make_float4(ep * s45.x + a[4], ep * s45.y + a[5],
                                             ep * s67.x + a[6], ep * s67.y + a[7]);
            if (q == 0)
                h[node * H1STR + 32] = ep * __half2float(xh32[node]) + a32;
        }
    }
}

// block-local bnstat recompute from bpart (fence-free; kernel-boundary ordered)
__device__ __forceinline__ void stat_prologue(const float* __restrict__ bpart,
                                              float* __restrict__ s_stat, int t) {
    __shared__ float red[256];
    int f = t & 31, g = t >> 5;
    float s = 0.f;
    for (int i = g; i < MLPB; i += 8) s += bpart[i * 32 + f];
    red[t] = s;
    __syncthreads();
    for (int off = 128; off >= 32; off >>= 1) {
        if (t < off) red[t] += red[t + off];
        __syncthreads();
    }
    if (t < 32) s_stat[t] = red[t];
    __syncthreads();
}

// ---------------- layer 2-5 aggregate (16 feats), BN folded (stats from bpart), dual-node ----------------
__global__ void __launch_bounds__(256) k_agg16(
    const __half* __restrict__ zh, const int* __restrict__ ptr,
    const unsigned* __restrict__ er,
    const float* __restrict__ ew, const float* __restrict__ ebv,
    const float* __restrict__ epsp,
    const float* __restrict__ bpart, const float* __restrict__ gamma,
    const float* __restrict__ beta, float* __restrict__ h) {
    __shared__ float s_stat[32];
    int t = threadIdx.x;
    stat_prologue(bpart, s_stat, t);
    int wave = t >> 6, lane = t & 63;
    int slot = lane >> 1, hh = lane & 1;
    float ep = 1.f + epsp[0];
    const float invn = 1.f / (float)N_NODES;
    float scf[8], shf[8], cbf[8], ewf[8];
    #pragma unroll
    for (int j = 0; j < 8; j++) {
        int f = hh * 8 + j;
        float mu = s_stat[f] * invn;
        float var = s_stat[DIM + f] * invn - mu * mu;
        float sc = gamma[f] * rsqrtf(var + BN_EPSV);
        scf[j] = sc;
        shf[j] = beta[f] - mu * sc;
        cbf[j] = shf[j] + ebv[f];
        ewf[j] = ew[f];
    }
    for (int quad = blockIdx.x; quad < NQUAD; quad += 2 * AGBLK) {
        int quadB = quad + AGBLK;
        bool hasB = quadB < NQUAD;
        int nodeA = quad * 4 + wave;
        int nodeB = hasB ? quadB * 4 + wave : nodeA;
        float a[8] = {0, 0, 0, 0, 0, 0, 0, 0};
        float b[8] = {0, 0, 0, 0, 0, 0, 0, 0};
        int e0a = ptr[nodeA], e1a = ptr[nodeA + 1];
        int e0b = ptr[nodeB], e1b = ptr[nodeB + 1];
        if (!hasB) e1b = e0b;
        int ia = e0a + slot, ib = e0b + slot;
        while (ia < e1a || ib < e1b) {
            bool da = ia < e1a, db = ib < e1b;
            unsigned evA = 0, evB = 0;
            if (da) evA = er[ia];
            if (db) evB = er[ib];
            uint4 rA, rB;
            float wvA = 0.f, wvB = 0.f;
            if (da) {
                rA = *(const uint4*)(zh + (evA & 0x1FFFF) * DIM + hh * 8);
                wvA = (float)(evA >> 17) * WDEC;
            }
            if (db) {
                rB = *(const uint4*)(zh + (evB & 0x1FFFF) * DIM + hh * 8);
                wvB = (float)(evB >> 17) * WDEC;
            }
            if (da) {
                float2 f01 = __half22float2(*(__half2*)&rA.x);
                float2 f23 = __half22float2(*(__half2*)&rA.y);
                float2 f45 = __half22float2(*(__half2*)&rA.z);
                float2 f67 = __half22float2(*(__half2*)&rA.w);
                float x[8] = {f01.x, f01.y, f23.x, f23.y, f45.x, f45.y, f67.x, f67.y};
                #pragma unroll
                for (int j = 0; j < 8; j++) {
                    float tb = fmaf(wvA, ewf[j], cbf[j]);
                    a[j] += fmaxf(fmaf(x[j], scf[j], tb), 0.f);
                }
            }
            if (db) {
                float2 f01 = __half22float2(*(__half2*)&rB.x);
                float2 f23 = __half22float2(*(__half2*)&rB.y);
                float2 f45 = __half22float2(*(__half2*)&rB.z);
                float2 f67 = __half22float2(*(__half2*)&rB.w);
                float x[8] = {f01.x, f01.y, f23.x, f23.y, f45.x, f45.y, f67.x, f67.y};
                #pragma unroll
                for (int j = 0; j < 8; j++) {
                    float tb = fmaf(wvB, ewf[j], cbf[j]);
                    b[j] += fmaxf(fmaf(x[j], scf[j], tb), 0.f);
                }
            }
            ia += 32; ib += 32;
        }
        #pragma unroll
        for (int m = 2; m <= 32; m <<= 1) {
            #pragma unroll
            for (int j = 0; j < 8; j++) {
                a[j] += __shfl_xor(a[j], m);
                b[j] += __shfl_xor(b[j], m);
            }
        }
        if (lane < 2) {
            {
                uint4 sraw = *(const uint4*)(zh + nodeA * DIM + lane * 8);
                float2 s01 = __half22float2(*(__half2*)&sraw.x);
                float2 s23 = __half22float2(*(__half2*)&sraw.y);
                float2 s45 = __half22float2(*(__half2*)&sraw.z);
                float2 s67 = __half22float2(*(__half2*)&sraw.w);
                float xs[8] = {s01.x, s01.y, s23.x, s23.y, s45.x, s45.y, s67.x, s67.y};
                float o8[8];
                #pragma unroll
                for (int j = 0; j < 8; j++)
                    o8[j] = ep * fmaf(xs[j], scf[j], shf[j]) + a[j];
                float* hp = h + nodeA * DIM + lane * 8;
                *(float4*)hp = make_float4(o8[0], o8[1], o8[2], o8[3]);
                *(float4*)(hp + 4) = make_float4(o8[4], o8[5], o8[6], o8[7]);
            }
            if (hasB) {
                uint4 sraw = *(const uint4*)(zh + nodeB * DIM + lane * 8);
                float2 s01 = __half22float2(*(__half2*)&sraw.x);
                float2 s23 = __half22float2(*(__half2*)&sraw.y);
                float2 s45 = __half22float2(*(__half2*)&sraw.z);
                float2 s67 = __half22float2(*(__half2*)&sraw.w);
                float xs[8] = {s01.x, s01.y, s23.x, s23.y, s45.x, s45.y, s67.x, s67.y};
                float o8[8];
                #pragma unroll
                for (int j = 0; j < 8; j++)
                    o8[j] = ep * fmaf(xs[j], scf[j], shf[j]) + b[j];
                float* hp = h + nodeB * DIM + lane * 8;
                *(float4*)hp = make_float4(o8[0], o8[1], o8[2], o8[3]);
                *(float4*)(hp + 4) = make_float4(o8[4], o8[5], o8[6], o8[7]);
            }
        }
    }
}

// ---------------- fused per-thread MLP + shfl-reduced BN partials, fp16 z out ----------------
__device__ __forceinline__ void mlp_bn_tail(float zv[16], bool active, int t,
                                            float* __restrict__ part) {
    __shared__ float red[4][32];
    float zs[16], zq[16];
    #pragma unroll
    for (int o = 0; o < 16; o++) {
        zs[o] = active ? zv[o] : 0.f;
        zq[o] = active ? zv[o] * zv[o] : 0.f;
    }
    #pragma unroll
    for (int m = 1; m <= 32; m <<= 1) {
        #pragma unroll
        for (int o = 0; o < 16; o++) {
            zs[o] += __shfl_xor(zs[o], m);
            zq[o] += __shfl_xor(zq[o], m);
        }
    }
    int wave = t >> 6, lane = t & 63;
    if (lane == 0) {
        #pragma unroll
        for (int o = 0; o < 16; o++) {
            red[wave][o] = zs[o];
            red[wave][16 + o] = zq[o];
        }
    }
    __syncthreads();
    if (t < 32)
        part[blockIdx.x * 32 + t] = red[0][t] + red[1][t] + red[2][t] + red[3][t];
}

__device__ __forceinline__ void store_zh(__half* __restrict__ zh, int n, float zv[16]) {
    __half2 p[8];
    #pragma unroll
    for (int j = 0; j < 8; j++) p[j] = __floats2half2_rn(zv[2 * j], zv[2 * j + 1]);
    *(uint4*)(zh + n * DIM) = *(uint4*)&p[0];
    *(uint4*)(zh + n * DIM + 8) = *(uint4*)&p[4];
}

__global__ void __launch_bounds__(256) k_mlp16(
    const float* __restrict__ h,
    const float* __restrict__ W1, const float* __restrict__ b1,
    const float* __restrict__ W2, const float* __restrict__ b2,
    __half* __restrict__ zh, float* __restrict__ part) {
    __shared__ float W1s[256], W2s[256], b1s[16], b2s[16];
    int t = threadIdx.x;
    W1s[t] = W1[t];
    W2s[t] = W2[t];
    if (t < 16) { b1s[t] = b1[t]; b2s[t] = b2[t]; }
    __syncthreads();
    int n = blockIdx.x * 256 + t;
    bool active = n < N_NODES;
    float zv[16];
    if (active) {
        float hv[16];
        #pragma unroll
        for (int j = 0; j < 4; j++) {
            float4 v = *(const float4*)(h + n * DIM + j * 4);
            hv[j * 4] = v.x; hv[j * 4 + 1] = v.y; hv[j * 4 + 2] = v.z; hv[j * 4 + 3] = v.w;
        }
        float tv[16];
        #pragma unroll
        for (int o = 0; o < 16; o++) {
            float s = b1s[o];
            #pragma unroll
            for (int f = 0; f < 16; f++) s += hv[f] * W1s[f * 16 + o];
            tv[o] = fmaxf(s, 0.f);
        }
        #pragma unroll
        for (int o = 0; o < 16; o++) {
            float s = b2s[o];
            #pragma unroll
            for (int f = 0; f < 16; f++) s += tv[f] * W2s[f * 16 + o];
            zv[o] = fmaxf(s, 0.f);
        }
        store_zh(zh, n, zv);
    }
    mlp_bn_tail(zv, active, t, part);
}

__global__ void __launch_bounds__(256) k_mlp1(
    const float* __restrict__ h,
    const float* __restrict__ W1, const float* __restrict__ b1,
    const float* __restrict__ W2, const float* __restrict__ b2,
    __half* __restrict__ zh, float* __restrict__ part) {
    __shared__ float W1s[NFP * 16], W2s[256], b1s[16], b2s[16];
    int t = threadIdx.x;
    for (int j = t; j < NFP * 16; j += 256) W1s[j] = W1[j];
    W2s[t] = W2[t];
    if (t < 16) { b1s[t] = b1[t]; b2s[t] = b2[t]; }
    __syncthreads();
    int n = blockIdx.x * 256 + t;
    bool active = n < N_NODES;
    float zv[16];
    if (active) {
        float hv[NFP];
        #pragma unroll
        for (int j = 0; j < 8; j++) {
            float4 v = *(const float4*)(h + n * H1STR + j * 4);
            hv[j * 4] = v.x; hv[j * 4 + 1] = v.y; hv[j * 4 + 2] = v.z; hv[j * 4 + 3] = v.w;
        }
        hv[32] = h[n * H1STR + 32];
        float tv[16];
        #pragma unroll
        for (int o = 0; o < 16; o++) {
            float s = b1s[o];
            #pragma unroll
            for (int f = 0; f < NFP; f++) s += hv[f] * W1s[f * 16 + o];
            tv[o] = fmaxf(s, 0.f);
        }
        #pragma unroll
        for (int o = 0; o < 16; o++) {
            float s = b2s[o];
            #pragma unroll
            for (int f = 0; f < 16; f++) s += tv[f] * W2s[f * 16 + o];
            zv[o] = fmaxf(s, 0.f);
        }
        store_zh(zh, n, zv);
    }
    mlp_bn_tail(zv, active, t, part);
}

// ---------------- pooling with BN folded (stats from bpart) ----------------
__global__ void __launch_bounds__(256) k_pool(const __half* __restrict__ zh,
                                              const int* __restrict__ batch,
                                              const float* __restrict__ bpart,
                                              const float* __restrict__ gamma,
                                              const float* __restrict__ beta,
                                              float* __restrict__ gsum,
                                              float* __restrict__ gcnt) {
    __shared__ float s_stat[32];
    __shared__ float lsum[BGR * DIM];
    __shared__ float lcnt[BGR];
    int t = threadIdx.x;
    stat_prologue(bpart, s_stat, t);
    for (int j = t; j < BGR * DIM; j += 256) lsum[j] = 0.f;
    if (t < BGR) lcnt[t] = 0.f;
    __syncthreads();
    int f = t & 15, r = t >> 4;
    const float invn = 1.f / (float)N_NODES;
    float mu = s_stat[f] * invn;
    float var = s_stat[DIM + f] * invn - mu * mu;
    float sc = gamma[f] * rsqrtf(var + BN_EPSV);
    float sh = beta[f] - mu * sc;
    int start = blockIdx.x * POOL_CHUNK;
    float acc = 0.f, cacc = 0.f;
    int cur = -1;
    for (int i = 0; i < POOL_CHUNK / 16; i++) {
        int n = start + r + i * 16;
        if (n >= N_NODES) break;
        int b = batch[n];
        if (b != cur) {
            if (cur >= 0) {
                atomicAdd(&lsum[cur * DIM + f], acc);
                if (f == 0) atomicAdd(&lcnt[cur], cacc);
            }
            cur = b; acc = 0.f; cacc = 0.f;
        }
        acc += fmaf(__half2float(zh[n * DIM + f]), sc, sh);
        cacc += 1.f;
    }
    if (cur >= 0) {
        atomicAdd(&lsum[cur * DIM + f], acc);
        if (f == 0) atomicAdd(&lcnt[cur], cacc);
    }
    __syncthreads();
    for (int j = t; j < BGR * DIM; j += 256) {
        float v = lsum[j];
        if (v != 0.f) atomicAdd(&gsum[j], v);
    }
    if (t < BGR) {
        float v = lcnt[t];
        if (v != 0.f) atomicAdd(&gcnt[t], v);
    }
}

__global__ void k_xp(const float* __restrict__ gsum, const float* __restrict__ gcnt,
                     const float* __restrict__ w, const float* __restrict__ bias,
                     float* __restrict__ out) {
    int b = blockIdx.x;
    int e = threadIdx.x;
    float inv = 1.f / fmaxf(gcnt[b], 1.f);
    float acc = bias[e];
    #pragma unroll
    for (int f = 0; f < DIM; f++) acc += gsum[b * DIM + f] * inv * w[f * EMB + e];
    out[b * EMB + e] = fmaxf(acc, 0.f);
}

// ---------------- RNA ----------------
__global__ void __launch_bounds__(256) k_bucket(const int* __restrict__ tok, int L, int V,
                                                int* __restrict__ blist,
                                                int* __restrict__ bptr) {
    __shared__ int hist[65];
    __shared__ int cursor[65];
    int b = blockIdx.x, t = threadIdx.x;
    if (t < V) hist[t] = 0;
    __syncthreads();
    for (int l = t; l < L; l += 256) atomicAdd(&hist[tok[b * L + l]], 1);
    __syncthreads();
    if (t == 0) {
        int run = 0;
        for (int v = 0; v < V; v++) {
            cursor[v] = run;
            bptr[b * (V + 1) + v] = run;
            run += hist[v];
        }
        bptr[b * (V + 1) + V] = run;
    }
    __syncthreads();
    for (int l = t; l < L; l += 256) {
        int v = tok[b * L + l];
        int p = atomicAdd(&cursor[v], 1);
        blist[b * L + p] = l;
    }
}

__global__ void __launch_bounds__(256) k_wsum(const int* __restrict__ blist,
                                              const int* __restrict__ bptr,
                                              const float* __restrict__ cw,
                                              float* __restrict__ W, int L, int V) {
    int b = blockIdx.x, v = blockIdx.y;
    int t = threadIdx.x, o = t >> 3, k = t & 7;
    int s = bptr[b * (V + 1) + v], e = bptr[b * (V + 1) + v + 1];
    __shared__ int tk[256];
    const float* cwp = cw + o * (L * KS) + k;
    float acc = 0.f;
    for (int j0 = s; j0 < e; j0 += 256) {
        int lim = e - j0; if (lim > 256) lim = 256;
        __syncthreads();
        if (t < lim) tk[t] = blist[b * L + j0 + t];
        __syncthreads();
        for (int j = 0; j < lim; j++) acc += cwp[tk[j] * KS];
    }
    W[((b * NF + o) * V + v) * KS + k] = acc;
}

__global__ void k_y(const float* __restrict__ Wg, const float* __restrict__ Wl,
                    const float* __restrict__ emb1, const float* __restrict__ emb2,
                    const float* __restrict__ cb1, const float* __restrict__ cb2,
                    float* __restrict__ yg, float* __restrict__ yl) {
    int which = blockIdx.y;
    int bo = blockIdx.x;
    int b = bo >> 5, o = bo & 31;
    int t = threadIdx.x;  // 128
    const float* W = which ? Wl : Wg;
    const float* emb = which ? emb2 : emb1;
    const float* cb = which ? cb2 : cb1;
    float* y = which ? yl : yg;
    int V = which ? 65 : 5;
    __shared__ float Wsh[65 * KS];
    const float* Wrow = W + (b * NF + o) * V * KS;
    for (int j = t; j < V * KS; j += 128) Wsh[j] = Wrow[j];
    __syncthreads();
    if (t < OUTT) {
        float acc = cb[o];
        for (int v = 0; v < V; v++) {
            const float* ep = emb + v * EMB + t;
            #pragma unroll
            for (int k = 0; k < KS; k++) acc += Wsh[v * KS + k] * ep[k];
        }
        y[(b * NF + o) * OUTT + t] = acc;
    }
}

__global__ void __launch_bounds__(128) k_fcpart(const float* __restrict__ yg,
                                                const float* __restrict__ yl,
                                                const float* __restrict__ w,
                                                float* __restrict__ partial) {
    int b = blockIdx.x, which = blockIdx.y, kc = blockIdx.z;
    const float* y = which ? yl : yg;
    int e = threadIdx.x;
    __shared__ float ych[KCH];
    int j0 = kc * KCH;
    if (e < KCH) ych[e] = y[b * FC_IN + j0 + e];
    __syncthreads();
    float acc = 0.f;
    #pragma unroll 4
    for (int jj = 0; jj < KCH; jj++) acc += ych[jj] * w[(j0 + jj) * EMB + e];
    partial[((which * BGR + b) * NKC + kc) * EMB + e] = acc;
}

__global__ void k_fcred(const float* __restrict__ partial, const float* __restrict__ bias,
                        float* __restrict__ out) {
    int b = blockIdx.x;
    int e = threadIdx.x;
    const float* pg = partial + b * NKC * EMB + e;
    const float* pl = partial + (BGR + b) * NKC * EMB + e;
    float ag = bias[e], al = bias[e];
    #pragma unroll
    for (int k = 0; k < NKC; k++) { ag += pg[k * EMB]; al += pl[k * EMB]; }
    out[b * EMB + e] = 0.5f * (ag + al);
}

extern "C" void kernel_launch(void* const* d_in, const int* in_sizes, int n_in,
                              void* d_out, int out_size, void* d_ws, size_t ws_size,
                              hipStream_t stream) {
    const float* pro_x = (const float*)d_in[0];
    const int* eidx = (const int*)d_in[1];
    const int* esrc = eidx;
    const int* edst = eidx + N_EDGES;
    const float* pw = (const float*)d_in[2];
    const int* batch = (const int*)d_in[3];
    const int* rg = (const int*)d_in[4];
    const int* rl = (const int*)d_in[5];
    const float* g1_w1 = (const float*)d_in[6];
    const float* g1_b1 = (const float*)d_in[7];
    const float* g1_w2 = (const float*)d_in[8];
    const float* g1_b2 = (const float*)d_in[9];
    const float* g1_ew = (const float*)d_in[10];
    const float* g1_eb = (const float*)d_in[11];
    const float* g1_eps = (const float*)d_in[12];
    const float* g_w1 = (const float*)d_in[13];
    const float* g_b1 = (const float*)d_in[14];
    const float* g_w2 = (const float*)d_in[15];
    const float* g_b2 = (const float*)d_in[16];
    const float* g_ew = (const float*)d_in[17];
    const float* g_eb = (const float*)d_in[18];
    const float* g_eps = (const float*)d_in[19];
    const float* bn_gamma = (const float*)d_in[20];
    const float* bn_beta = (const float*)d_in[21];
    const float* fc1_xp_w = (const float*)d_in[22];
    const float* fc1_xp_b = (const float*)d_in[23];
    const float* emb1 = (const float*)d_in[24];
    const float* emb2 = (const float*)d_in[25];
    const float* convr1_w = (const float*)d_in[26];
    const float* convr1_b = (const float*)d_in[27];
    const float* convr2_w = (const float*)d_in[28];
    const float* convr2_b = (const float*)d_in[29];
    const float* fcxr_w = (const float*)d_in[30];
    const float* fcxr_b = (const float*)d_in[31];
    float* out = (float*)d_out;

    // persistent buffers
    float* wsf = (float*)d_ws;
    int* ptr       = (int*)wsf;        wsf += 100128;
    int* binoff    = (int*)wsf;        wsf += 512;
    int* bincur    = (int*)wsf;        wsf += 512;
    unsigned* er   = (unsigned*)wsf;   wsf += 2 * N_EDGES;
    float* stats   = wsf;              wsf += 1280;
    // union region
    float* un = wsf;
    int2* tmp_sw          = (int2*)un;
    int* bh               = (int*)(un + 7200000);
    __half* zh   = (__half*)(un + 1600000);
    __half* xh1  = (__half*)(un + 2400000);
    __half* xh32 = (__half*)(un + 4000000);
    float* bpart = un + 4100000;
    float* Wg    = un + 4300000;
    float* Wl    = un + 4382000;
    float* yg    = un + 5447000;
    float* yl    = un + 5695000;
    int* blg     = (int*)(un + 5961000);
    int* bll     = (int*)(un + 6153000);
    int* bpg     = (int*)(un + 6345000);
    int* bpl     = (int*)(un + 6346000);
    float* fcpart = un + 6360000;
    float* h      = un + 7400000;
    float* gsum   = stats;
    float* gcnt   = stats + 1024;

    hipMemsetAsync(stats, 0, 1280 * sizeof(float), stream);

    // CSR build
    k_bincnt<<<BCNT_BLK, 256, 0, stream>>>(edst, bh);
    k_binscan<<<1, 512, 0, stream>>>(bh, binoff, bincur);
    k_part1<<<P1_BLOCKS, 256, 0, stream>>>(esrc, edst, pw, bincur, tmp_sw);
    k_part2<<<NBIN, 256, 0, stream>>>(tmp_sw, binoff, er, ptr);

    // pro_x -> fp16 rows
    k_half1<<<(N_NODES * NFP + 255) / 256, 256, 0, stream>>>(pro_x, xh1, xh32);

    // RNA branch
    k_bucket<<<BGR, 256, 0, stream>>>(rg, MAXLEN, 5, blg, bpg);
    k_bucket<<<BGR, 256, 0, stream>>>(rl, LOCLEN, 65, bll, bpl);
    k_wsum<<<dim3(BGR, 5), 256, 0, stream>>>(blg, bpg, convr1_w, Wg, MAXLEN, 5);
    k_wsum<<<dim3(BGR, 65), 256, 0, stream>>>(bll, bpl, convr2_w, Wl, LOCLEN, 65);
    k_y<<<dim3(BGR * NF, 2), 128, 0, stream>>>(Wg, Wl, emb1, emb2, convr1_b, convr2_b, yg, yl);
    k_fcpart<<<dim3(BGR, 2, NKC), 128, 0, stream>>>(yg, yl, fcxr_w, fcpart);
    k_fcred<<<BGR, 128, 0, stream>>>(fcpart, fcxr_b, out);

    // GNN stack: agg -> mlp (BN stats recomputed from bpart by consumers; no bnred launches)
    k_agg1<<<AGBLK, 256, 0, stream>>>(xh1, xh32, ptr, er, g1_ew, g1_eb, g1_eps, h);
    k_mlp1<<<MLPB, 256, 0, stream>>>(h, g1_w1, g1_b1, g1_w2, g1_b2, zh, bpart);
    for (int i = 0; i < 4; i++) {
        k_agg16<<<AGBLK, 256, 0, stream>>>(zh, ptr, er,
                                           g_ew + i * DIM, g_eb + i * DIM, g_eps + i,
                                           bpart, bn_gamma + i * DIM,
                                           bn_beta + i * DIM, h);
        k_mlp16<<<MLPB, 256, 0, stream>>>(h, g_w1 + i * DIM * DIM, g_b1 + i * DIM,
                                          g_w2 + i * DIM * DIM, g_b2 + i * DIM, zh, bpart);
    }
    k_pool<<<POOL_BLKS, 256, 0, stream>>>(zh, batch, bpart,
                                          bn_gamma + 4 * DIM, bn_beta + 4 * DIM, gsum, gcnt);
    k_xp<<<BGR, EMB, 0, stream>>>(gsum, gcnt, fc1_xp_w, fc1_xp_b, out + BGR * EMB);
}

// Round 19
// 773.863 us; speedup vs baseline: 4.1085x; 1.1040x over previous
//
#include <hip/hip_runtime.h>
#include <hip/hip_fp16.h>

#define N_NODES 100000
#define N_EDGES 3200000
#define BGR 64
#define DIM 16
#define NFP 33
#define ROW1 32
#define H1STR 36
#define EMB 128
#define MAXLEN 3000
#define LOCLEN 2998
#define NF 32
#define KS 8
#define OUTT 121
#define FC_IN 3872
#define BN_EPSV 1e-5f
#define POOL_CHUNK 256
#define POOL_BLKS 391
#define NQUAD 25000
#define AGBLK 2048
#define MLPB 391
// binned CSR build
#define NBIN 391
#define BCNT_BLK 512
#define P1_CHUNK 4096
#define P1_BLOCKS 782
#define MAXBIN 9088
// fc K-split
#define NKC 32
#define KCH 121
#define WDEC (1.f / 32767.f)

// ---------------- CSR build ----------------
__global__ void __launch_bounds__(256) k_bincnt(const int* __restrict__ dst,
                                                int* __restrict__ bh) {
    __shared__ int hist[NBIN];
    int t = threadIdx.x, bid = blockIdx.x;
    for (int b = t; b < NBIN; b += 256) hist[b] = 0;
    __syncthreads();
    int e0 = bid * (N_EDGES / BCNT_BLK);
    int e1 = e0 + (N_EDGES / BCNT_BLK);
    for (int e = e0 + t; e < e1; e += 256) atomicAdd(&hist[dst[e] >> 8], 1);
    __syncthreads();
    for (int b = t; b < NBIN; b += 256) bh[b * BCNT_BLK + bid] = hist[b];
}

__global__ void __launch_bounds__(512) k_binscan(const int* __restrict__ bh,
                                                 int* __restrict__ binoff,
                                                 int* __restrict__ bincur) {
    __shared__ int sc[512];
    int t = threadIdx.x;
    int s = 0;
    if (t < NBIN) {
        const int* row = bh + t * BCNT_BLK;
        for (int k = 0; k < BCNT_BLK; k++) s += row[k];
    }
    sc[t] = s;
    __syncthreads();
    for (int off = 1; off < 512; off <<= 1) {
        int v = (t >= off) ? sc[t - off] : 0;
        __syncthreads();
        sc[t] += v;
        __syncthreads();
    }
    int excl = sc[t] - s;
    if (t <= NBIN) binoff[t] = excl;
    if (t < NBIN) bincur[t] = excl;
}

// pass 1: single coalesced read -> LDS-staged records -> LDS rank -> coalesced write.
__global__ void __launch_bounds__(256) k_part1(const int* __restrict__ src,
                                               const int* __restrict__ dst,
                                               const float* __restrict__ w,
                                               int* __restrict__ bincur,
                                               int2* __restrict__ tmp_sw) {
    __shared__ int2 srec[P1_CHUNK];
    __shared__ unsigned short sbin[P1_CHUNK];
    __shared__ unsigned short sperm[P1_CHUNK];
    __shared__ int hist[NBIN];
    __shared__ int off[NBIN];
    __shared__ int cur[NBIN];
    __shared__ int base[NBIN];
    __shared__ int sc[512];
    int t = threadIdx.x;
    int g0 = blockIdx.x * P1_CHUNK;
    int cn = N_EDGES - g0; if (cn > P1_CHUNK) cn = P1_CHUNK;
    for (int b = t; b < NBIN; b += 256) hist[b] = 0;
    __syncthreads();
    for (int j = t; j < cn; j += 256) {
        int d = dst[g0 + j];
        int b = d >> 8;
        sbin[j] = (unsigned short)b;
        srec[j] = make_int2(src[g0 + j] | ((d & 255) << 20), __float_as_int(w[g0 + j]));
        atomicAdd(&hist[b], 1);
    }
    __syncthreads();
    sc[t] = (t < NBIN) ? hist[t] : 0;
    sc[256 + t] = (256 + t < NBIN) ? hist[256 + t] : 0;
    __syncthreads();
    for (int o = 1; o <= 256; o <<= 1) {
        int v0 = (t >= o) ? sc[t - o] : 0;
        int v1 = sc[256 + t - o];
        __syncthreads();
        sc[t] += v0;
        sc[256 + t] += v1;
        __syncthreads();
    }
    for (int b = t; b < NBIN; b += 256) {
        int e = sc[b] - hist[b];
        off[b] = e;
        cur[b] = e;
        int c = hist[b];
        base[b] = c ? atomicAdd(&bincur[b], c) : 0;
    }
    __syncthreads();
    for (int j = t; j < cn; j += 256) {
        int p = atomicAdd(&cur[sbin[j]], 1);
        sperm[p] = (unsigned short)j;
    }
    __syncthreads();
    for (int p = t; p < cn; p += 256) {
        int j = sperm[p];
        int b = sbin[j];
        tmp_sw[base[b] + (p - off[b])] = srec[j];
    }
}

// pass 2: per-bin fine sort + ptr; emit compact 4B edge records src(17) | wq(15)
__global__ void __launch_bounds__(256) k_part2(const int2* __restrict__ tmp_sw,
                                               const int* __restrict__ binoff,
                                               unsigned* __restrict__ er,
                                               int* __restrict__ ptr) {
    __shared__ unsigned char sdl[MAXBIN];
    __shared__ unsigned short perm[MAXBIN];
    __shared__ int hist[256];
    __shared__ int cur[256];
    __shared__ int sc[256];
    int t = threadIdx.x, b = blockIdx.x;
    int nlo = b << 8;
    int e0 = binoff[b], e1 = binoff[b + 1];
    int cnt = e1 - e0;
    int stage = cnt < MAXBIN ? cnt : MAXBIN;
    hist[t] = 0;
    __syncthreads();
    for (int j = t; j < stage; j += 256) {
        unsigned char dl = (unsigned char)((tmp_sw[e0 + j].x >> 20) & 255);
        sdl[j] = dl;
        atomicAdd(&hist[dl], 1);
    }
    for (int j = stage + t; j < cnt; j += 256)
        atomicAdd(&hist[(tmp_sw[e0 + j].x >> 20) & 255], 1);
    __syncthreads();
    int v = hist[t];
    sc[t] = v;
    __syncthreads();
    for (int off = 1; off < 256; off <<= 1) {
        int u = (t >= off) ? sc[t - off] : 0;
        __syncthreads();
        sc[t] += u;
        __syncthreads();
    }
    int excl = sc[t] - v;
    cur[t] = excl;
    if (nlo + t < N_NODES) ptr[nlo + t] = e0 + excl;
    if (b == NBIN - 1 && t == 0) ptr[N_NODES] = N_EDGES;
    __syncthreads();
    for (int j = t; j < stage; j += 256) {
        int p = atomicAdd(&cur[sdl[j]], 1);
        perm[p] = (unsigned short)j;
    }
    __syncthreads();
    for (int j = stage + t; j < cnt; j += 256) {
        int2 sw = tmp_sw[e0 + j];
        int p = atomicAdd(&cur[(sw.x >> 20) & 255], 1);
        unsigned wq = (unsigned)(__int_as_float(sw.y) * 32767.f + 0.5f);
        er[e0 + p] = ((unsigned)sw.x & 0x1FFFFu) | (wq << 17);
    }
    for (int p = t; p < stage; p += 256) {
        int2 sw = tmp_sw[e0 + perm[p]];
        unsigned wq = (unsigned)(__int_as_float(sw.y) * 32767.f + 0.5f);
        er[e0 + p] = ((unsigned)sw.x & 0x1FFFFu) | (wq << 17);
    }
}

// ---------------- fp16 conversion of pro_x ----------------
__global__ void k_half1(const float* __restrict__ x, __half* __restrict__ xh,
                        __half* __restrict__ xh32) {
    int i = blockIdx.x * blockDim.x + threadIdx.x;
    if (i < N_NODES * NFP) {
        int n = i / NFP, f = i - n * NFP;
        __half v = __float2half(x[i]);
        if (f < 32) xh[n * ROW1 + f] = v;
        else xh32[n] = v;
    }
}

// ---------------- layer-1 aggregate (33 feats), single-node ----------------
__global__ void __launch_bounds__(256) k_agg1(
    const __half* __restrict__ xh, const __half* __restrict__ xh32,
    const int* __restrict__ ptr, const unsigned* __restrict__ er,
    const float* __restrict__ ew, const float* __restrict__ ebv,
    const float* __restrict__ epsp, float* __restrict__ h) {
    int t = threadIdx.x;
    int wave = t >> 6, lane = t & 63;
    int slot = lane >> 2, q = lane & 3;
    float4 ewa = ((const float4*)ew)[q * 2];
    float4 ewb = ((const float4*)ew)[q * 2 + 1];
    float4 eba = ((const float4*)ebv)[q * 2];
    float4 ebb = ((const float4*)ebv)[q * 2 + 1];
    float ew32 = ew[32], eb32 = ebv[32];
    float ep = 1.f + epsp[0];
    for (int quad = blockIdx.x; quad < NQUAD; quad += AGBLK) {
        int node = quad * 4 + wave;
        float a[8] = {0, 0, 0, 0, 0, 0, 0, 0};
        float a32 = 0.f;
        int e0 = ptr[node], e1 = ptr[node + 1];
        for (int i = e0 + slot; i < e1; i += 16) {
            unsigned ev = er[i];
            int s = ev & 0x1FFFF;
            float wv = (float)(ev >> 17) * WDEC;
            uint4 raw = *(const uint4*)(xh + s * ROW1 + q * 8);
            float2 f01 = __half22float2(*(__half2*)&raw.x);
            float2 f23 = __half22float2(*(__half2*)&raw.y);
            float2 f45 = __half22float2(*(__half2*)&raw.z);
            float2 f67 = __half22float2(*(__half2*)&raw.w);
            a[0] += fmaxf(f01.x + wv * ewa.x + eba.x, 0.f);
            a[1] += fmaxf(f01.y + wv * ewa.y + eba.y, 0.f);
            a[2] += fmaxf(f23.x + wv * ewa.z + eba.z, 0.f);
            a[3] += fmaxf(f23.y + wv * ewa.w + eba.w, 0.f);
            a[4] += fmaxf(f45.x + wv * ewb.x + ebb.x, 0.f);
            a[5] += fmaxf(f45.y + wv * ewb.y + ebb.y, 0.f);
            a[6] += fmaxf(f67.x + wv * ewb.z + ebb.z, 0.f);
            a[7] += fmaxf(f67.y + wv * ewb.w + ebb.w, 0.f);
            if (q == 0) a32 += fmaxf(__half2float(xh32[s]) + wv * ew32 + eb32, 0.f);
        }
        #pragma unroll
        for (int m = 4; m <= 32; m <<= 1) {
            #pragma unroll
            for (int j = 0; j < 8; j++) a[j] += __shfl_xor(a[j], m);
            a32 += __shfl_xor(a32, m);
        }
        if (slot == 0) {
            uint4 sraw = *(const uint4*)(xh + node * ROW1 + q * 8);
            float2 s01 = __half22float2(*(__half2*)&sraw.x);
            float2 s23 = __half22float2(*(__half2*)&sraw.y);
            float2 s45 = __half22float2(*(__half2*)&sraw.z);
            float2 s67 = __half22float2(*(__half2*)&sraw.w);
            float* hp = h + node * H1STR + q * 8;
            *(float4*)hp = make_float4(ep * s01.x + a[0], ep * s01.y + a[1],
                                       ep * s23.x + a[2], ep * s23.y + a[3]);
            *(float4*)(hp + 4) = make_float4(ep * s45.x + a[4], ep * s45.y + a[5],
                                             ep * s67.x + a[6], ep * s67.y + a[7]);
            if (q == 0)
                h[node * H1STR + 32] = ep * __half2float(xh32[node]) + a32;
        }
    }
}

// ---------------- layer 2-5 aggregate (16 feats), BN folded, dual-node ----------------
__global__ void __launch_bounds__(256) k_agg16(
    const __half* __restrict__ zh, const int* __restrict__ ptr,
    const unsigned* __restrict__ er,
    const float* __restrict__ ew, const float* __restrict__ ebv,
    const float* __restrict__ epsp,
    const float* __restrict__ bnstat, const float* __restrict__ gamma,
    const float* __restrict__ beta, float* __restrict__ h) {
    int t = threadIdx.x;
    int wave = t >> 6, lane = t & 63;
    int slot = lane >> 1, hh = lane & 1;
    float ep = 1.f + epsp[0];
    const float invn = 1.f / (float)N_NODES;
    float scf[8], shf[8], cbf[8], ewf[8];
    #pragma unroll
    for (int j = 0; j < 8; j++) {
        int f = hh * 8 + j;
        float mu = bnstat[f] * invn;
        float var = bnstat[DIM + f] * invn - mu * mu;
        float sc = gamma[f] * rsqrtf(var + BN_EPSV);
        scf[j] = sc;
        shf[j] = beta[f] - mu * sc;
        cbf[j] = shf[j] + ebv[f];
        ewf[j] = ew[f];
    }
    for (int quad = blockIdx.x; quad < NQUAD; quad += 2 * AGBLK) {
        int quadB = quad + AGBLK;
        bool hasB = quadB < NQUAD;
        int nodeA = quad * 4 + wave;
        int nodeB = hasB ? quadB * 4 + wave : nodeA;
        float a[8] = {0, 0, 0, 0, 0, 0, 0, 0};
        float b[8] = {0, 0, 0, 0, 0, 0, 0, 0};
        int e0a = ptr[nodeA], e1a = ptr[nodeA + 1];
        int e0b = ptr[nodeB], e1b = ptr[nodeB + 1];
        if (!hasB) e1b = e0b;
        int ia = e0a + slot, ib = e0b + slot;
        while (ia < e1a || ib < e1b) {
            bool da = ia < e1a, db = ib < e1b;
            unsigned evA = 0, evB = 0;
            if (da) evA = er[ia];
            if (db) evB = er[ib];
            uint4 rA, rB;
            float wvA = 0.f, wvB = 0.f;
            if (da) {
                rA = *(const uint4*)(zh + (evA & 0x1FFFF) * DIM + hh * 8);
                wvA = (float)(evA >> 17) * WDEC;
            }
            if (db) {
                rB = *(const uint4*)(zh + (evB & 0x1FFFF) * DIM + hh * 8);
                wvB = (float)(evB >> 17) * WDEC;
            }
            if (da) {
                float2 f01 = __half22float2(*(__half2*)&rA.x);
                float2 f23 = __half22float2(*(__half2*)&rA.y);
                float2 f45 = __half22float2(*(__half2*)&rA.z);
                float2 f67 = __half22float2(*(__half2*)&rA.w);
                float x[8] = {f01.x, f01.y, f23.x, f23.y, f45.x, f45.y, f67.x, f67.y};
                #pragma unroll
                for (int j = 0; j < 8; j++) {
                    float tb = fmaf(wvA, ewf[j], cbf[j]);
                    a[j] += fmaxf(fmaf(x[j], scf[j], tb), 0.f);
                }
            }
            if (db) {
                float2 f01 = __half22float2(*(__half2*)&rB.x);
                float2 f23 = __half22float2(*(__half2*)&rB.y);
                float2 f45 = __half22float2(*(__half2*)&rB.z);
                float2 f67 = __half22float2(*(__half2*)&rB.w);
                float x[8] = {f01.x, f01.y, f23.x, f23.y, f45.x, f45.y, f67.x, f67.y};
                #pragma unroll
                for (int j = 0; j < 8; j++) {
                    float tb = fmaf(wvB, ewf[j], cbf[j]);
                    b[j] += fmaxf(fmaf(x[j], scf[j], tb), 0.f);
                }
            }
            ia += 32; ib += 32;
        }
        #pragma unroll
        for (int m = 2; m <= 32; m <<= 1) {
            #pragma unroll
            for (int j = 0; j < 8; j++) {
                a[j] += __shfl_xor(a[j], m);
                b[j] += __shfl_xor(b[j], m);
            }
        }
        if (lane < 2) {
            {
                uint4 sraw = *(const uint4*)(zh + nodeA * DIM + lane * 8);
                float2 s01 = __half22float2(*(__half2*)&sraw.x);
                float2 s23 = __half22float2(*(__half2*)&sraw.y);
                float2 s45 = __half22float2(*(__half2*)&sraw.z);
                float2 s67 = __half22float2(*(__half2*)&sraw.w);
                float xs[8] = {s01.x, s01.y, s23.x, s23.y, s45.x, s45.y, s67.x, s67.y};
                float o8[8];
                #pragma unroll
                for (int j = 0; j < 8; j++)
                    o8[j] = ep * fmaf(xs[j], scf[j], shf[j]) + a[j];
                float* hp = h + nodeA * DIM + lane * 8;
                *(float4*)hp = make_float4(o8[0], o8[1], o8[2], o8[3]);
                *(float4*)(hp + 4) = make_float4(o8[4], o8[5], o8[6], o8[7]);
            }
            if (hasB) {
                uint4 sraw = *(const uint4*)(zh + nodeB * DIM + lane * 8);
                float2 s01 = __half22float2(*(__half2*)&sraw.x);
                float2 s23 = __half22float2(*(__half2*)&sraw.y);
                float2 s45 = __half22float2(*(__half2*)&sraw.z);
                float2 s67 = __half22float2(*(__half2*)&sraw.w);
                float xs[8] = {s01.x, s01.y, s23.x, s23.y, s45.x, s45.y, s67.x, s67.y};
                float o8[8];
                #pragma unroll
                for (int j = 0; j < 8; j++)
                    o8[j] = ep * fmaf(xs[j], scf[j], shf[j]) + b[j];
                float* hp = h + nodeB * DIM + lane * 8;
                *(float4*)hp = make_float4(o8[0], o8[1], o8[2], o8[3]);
                *(float4*)(hp + 4) = make_float4(o8[4], o8[5], o8[6], o8[7]);
            }
        }
    }
}

// ---------------- fused per-thread MLP + shfl-reduced BN partials, fp16 z out ----------------
__device__ __forceinline__ void mlp_bn_tail(float zv[16], bool active, int t,
                                            float* __restrict__ part) {
    __shared__ float red[4][32];
    float zs[16], zq[16];
    #pragma unroll
    for (int o = 0; o < 16; o++) {
        zs[o] = active ? zv[o] : 0.f;
        zq[o] = active ? zv[o] * zv[o] : 0.f;
    }
    #pragma unroll
    for (int m = 1; m <= 32; m <<= 1) {
        #pragma unroll
        for (int o = 0; o < 16; o++) {
            zs[o] += __shfl_xor(zs[o], m);
            zq[o] += __shfl_xor(zq[o], m);
        }
    }
    int wave = t >> 6, lane = t & 63;
    if (lane == 0) {
        #pragma unroll
        for (int o = 0; o < 16; o++) {
            red[wave][o] = zs[o];
            red[wave][16 + o] = zq[o];
        }
    }
    __syncthreads();
    if (t < 32)
        part[blockIdx.x * 32 + t] = red[0][t] + red[1][t] + red[2][t] + red[3][t];
}

__device__ __forceinline__ void store_zh(__half* __restrict__ zh, int n, float zv[16]) {
    __half2 p[8];
    #pragma unroll
    for (int j = 0; j < 8; j++) p[j] = __floats2half2_rn(zv[2 * j], zv[2 * j + 1]);
    *(uint4*)(zh + n * DIM) = *(uint4*)&p[0];
    *(uint4*)(zh + n * DIM + 8) = *(uint4*)&p[4];
}

__global__ void __launch_bounds__(256) k_mlp16(
    const float* __restrict__ h,
    const float* __restrict__ W1, const float* __restrict__ b1,
    const float* __restrict__ W2, const float* __restrict__ b2,
    __half* __restrict__ zh, float* __restrict__ part) {
    __shared__ float W1s[256], W2s[256], b1s[16], b2s[16];
    int t = threadIdx.x;
    W1s[t] = W1[t];
    W2s[t] = W2[t];
    if (t < 16) { b1s[t] = b1[t]; b2s[t] = b2[t]; }
    __syncthreads();
    int n = blockIdx.x * 256 + t;
    bool active = n < N_NODES;
    float zv[16];
    if (active) {
        float hv[16];
        #pragma unroll
        for (int j = 0; j < 4; j++) {
            float4 v = *(const float4*)(h + n * DIM + j * 4);
            hv[j * 4] = v.x; hv[j * 4 + 1] = v.y; hv[j * 4 + 2] = v.z; hv[j * 4 + 3] = v.w;
        }
        float tv[16];
        #pragma unroll
        for (int o = 0; o < 16; o++) {
            float s = b1s[o];
            #pragma unroll
            for (int f = 0; f < 16; f++) s += hv[f] * W1s[f * 16 + o];
            tv[o] = fmaxf(s, 0.f);
        }
        #pragma unroll
        for (int o = 0; o < 16; o++) {
            float s = b2s[o];
            #pragma unroll
            for (int f = 0; f < 16; f++) s += tv[f] * W2s[f * 16 + o];
            zv[o] = fmaxf(s, 0.f);
        }
        store_zh(zh, n, zv);
    }
    mlp_bn_tail(zv, active, t, part);
}

__global__ void __launch_bounds__(256) k_mlp1(
    const float* __restrict__ h,
    const float* __restrict__ W1, const float* __restrict__ b1,
    const float* __restrict__ W2, const float* __restrict__ b2,
    __half* __restrict__ zh, float* __restrict__ part) {
    __shared__ float W1s[NFP * 16], W2s[256], b1s[16], b2s[16];
    int t = threadIdx.x;
    for (int j = t; j < NFP * 16; j += 256) W1s[j] = W1[j];
    W2s[t] = W2[t];
    if (t < 16) { b1s[t] = b1[t]; b2s[t] = b2[t]; }
    __syncthreads();
    int n = blockIdx.x * 256 + t;
    bool active = n < N_NODES;
    float zv[16];
    if (active) {
        float hv[NFP];
        #pragma unroll
        for (int j = 0; j < 8; j++) {
            float4 v = *(const float4*)(h + n * H1STR + j * 4);
            hv[j * 4] = v.x; hv[j * 4 + 1] = v.y; hv[j * 4 + 2] = v.z; hv[j * 4 + 3] = v.w;
        }
        hv[32] = h[n * H1STR + 32];
        float tv[16];
        #pragma unroll
        for (int o = 0; o < 16; o++) {
            float s = b1s[o];
            #pragma unroll
            for (int f = 0; f < NFP; f++) s += hv[f] * W1s[f * 16 + o];
            tv[o] = fmaxf(s, 0.f);
        }
        #pragma unroll
        for (int o = 0; o < 16; o++) {
            float s = b2s[o];
            #pragma unroll
            for (int f = 0; f < 16; f++) s += tv[f] * W2s[f * 16 + o];
            zv[o] = fmaxf(s, 0.f);
        }
        store_zh(zh, n, zv);
    }
    mlp_bn_tail(zv, active, t, part);
}

// ---------------- reduce block partials -> bnstat[32] ----------------
__global__ void __launch_bounds__(1024) k_bnred(const float* __restrict__ part,
                                                float* __restrict__ bnstat) {
    __shared__ float red[1024];
    int t = threadIdx.x;
    int f = t & 31, g = t >> 5;
    float s = 0.f;
    for (int i = g; i < MLPB; i += 32) s += part[i * 32 + f];
    red[t] = s;
    __syncthreads();
    for (int off = 512; off >= 32; off >>= 1) {
        if (t < off) red[t] += red[t + off];
        __syncthreads();
    }
    if (t < 32) bnstat[t] = red[t];
}

// ---------------- pooling with BN folded in ----------------
__global__ void __launch_bounds__(256) k_pool(const __half* __restrict__ zh,
                                              const int* __restrict__ batch,
                                              const float* __restrict__ bnstat,
                                              const float* __restrict__ gamma,
                                              const float* __restrict__ beta,
                                              float* __restrict__ gsum,
                                              float* __restrict__ gcnt) {
    __shared__ float lsum[BGR * DIM];
    __shared__ float lcnt[BGR];
    int t = threadIdx.x;
    for (int j = t; j < BGR * DIM; j += 256) lsum[j] = 0.f;
    if (t < BGR) lcnt[t] = 0.f;
    __syncthreads();
    int f = t & 15, r = t >> 4;
    const float invn = 1.f / (float)N_NODES;
    float mu = bnstat[f] * invn;
    float var = bnstat[DIM + f] * invn - mu * mu;
    float sc = gamma[f] * rsqrtf(var + BN_EPSV);
    float sh = beta[f] - mu * sc;
    int start = blockIdx.x * POOL_CHUNK;
    float acc = 0.f, cacc = 0.f;
    int cur = -1;
    for (int i = 0; i < POOL_CHUNK / 16; i++) {
        int n = start + r + i * 16;
        if (n >= N_NODES) break;
        int b = batch[n];
        if (b != cur) {
            if (cur >= 0) {
                atomicAdd(&lsum[cur * DIM + f], acc);
                if (f == 0) atomicAdd(&lcnt[cur], cacc);
            }
            cur = b; acc = 0.f; cacc = 0.f;
        }
        acc += fmaf(__half2float(zh[n * DIM + f]), sc, sh);
        cacc += 1.f;
    }
    if (cur >= 0) {
        atomicAdd(&lsum[cur * DIM + f], acc);
        if (f == 0) atomicAdd(&lcnt[cur], cacc);
    }
    __syncthreads();
    for (int j = t; j < BGR * DIM; j += 256) {
        float v = lsum[j];
        if (v != 0.f) atomicAdd(&gsum[j], v);
    }
    if (t < BGR) {
        float v = lcnt[t];
        if (v != 0.f) atomicAdd(&gcnt[t], v);
    }
}

__global__ void k_xp(const float* __restrict__ gsum, const float* __restrict__ gcnt,
                     const float* __restrict__ w, const float* __restrict__ bias,
                     float* __restrict__ out) {
    int b = blockIdx.x;
    int e = threadIdx.x;
    float inv = 1.f / fmaxf(gcnt[b], 1.f);
    float acc = bias[e];
    #pragma unroll
    for (int f = 0; f < DIM; f++) acc += gsum[b * DIM + f] * inv * w[f * EMB + e];
    out[b * EMB + e] = fmaxf(acc, 0.f);
}

// ---------------- RNA ----------------
__global__ void __launch_bounds__(256) k_bucket(const int* __restrict__ tok, int L, int V,
                                                int* __restrict__ blist,
                                                int* __restrict__ bptr) {
    __shared__ int hist[65];
    __shared__ int cursor[65];
    int b = blockIdx.x, t = threadIdx.x;
    if (t < V) hist[t] = 0;
    __syncthreads();
    for (int l = t; l < L; l += 256) atomicAdd(&hist[tok[b * L + l]], 1);
    __syncthreads();
    if (t == 0) {
        int run = 0;
        for (int v = 0; v < V; v++) {
            cursor[v] = run;
            bptr[b * (V + 1) + v] = run;
            run += hist[v];
        }
        bptr[b * (V + 1) + V] = run;
    }
    __syncthreads();
    for (int l = t; l < L; l += 256) {
        int v = tok[b * L + l];
        int p = atomicAdd(&cursor[v], 1);
        blist[b * L + p] = l;
    }
}

__global__ void __launch_bounds__(256) k_wsum(const int* __restrict__ blist,
                                              const int* __restrict__ bptr,
                                              const float* __restrict__ cw,
                                              float* __restrict__ W, int L, int V) {
    int b = blockIdx.x, v = blockIdx.y;
    int t = threadIdx.x, o = t >> 3, k = t & 7;
    int s = bptr[b * (V + 1) + v], e = bptr[b * (V + 1) + v + 1];
    __shared__ int tk[256];
    const float* cwp = cw + o * (L * KS) + k;
    float acc = 0.f;
    for (int j0 = s; j0 < e; j0 += 256) {
        int lim = e - j0; if (lim > 256) lim = 256;
        __syncthreads();
        if (t < lim) tk[t] = blist[b * L + j0 + t];
        __syncthreads();
        for (int j = 0; j < lim; j++) acc += cwp[tk[j] * KS];
    }
    W[((b * NF + o) * V + v) * KS + k] = acc;
}

__global__ void k_y(const float* __restrict__ Wg, const float* __restrict__ Wl,
                    const float* __restrict__ emb1, const float* __restrict__ emb2,
                    const float* __restrict__ cb1, const float* __restrict__ cb2,
                    float* __restrict__ yg, float* __restrict__ yl) {
    int which = blockIdx.y;
    int bo = blockIdx.x;
    int b = bo >> 5, o = bo & 31;
    int t = threadIdx.x;  // 128
    const float* W = which ? Wl : Wg;
    const float* emb = which ? emb2 : emb1;
    const float* cb = which ? cb2 : cb1;
    float* y = which ? yl : yg;
    int V = which ? 65 : 5;
    __shared__ float Wsh[65 * KS];
    const float* Wrow = W + (b * NF + o) * V * KS;
    for (int j = t; j < V * KS; j += 128) Wsh[j] = Wrow[j];
    __syncthreads();
    if (t < OUTT) {
        float acc = cb[o];
        for (int v = 0; v < V; v++) {
            const float* ep = emb + v * EMB + t;
            #pragma unroll
            for (int k = 0; k < KS; k++) acc += Wsh[v * KS + k] * ep[k];
        }
        y[(b * NF + o) * OUTT + t] = acc;
    }
}

__global__ void __launch_bounds__(128) k_fcpart(const float* __restrict__ yg,
                                                const float* __restrict__ yl,
                                                const float* __restrict__ w,
                                                float* __restrict__ partial) {
    int b = blockIdx.x, which = blockIdx.y, kc = blockIdx.z;
    const float* y = which ? yl : yg;
    int e = threadIdx.x;
    __shared__ float ych[KCH];
    int j0 = kc * KCH;
    if (e < KCH) ych[e] = y[b * FC_IN + j0 + e];
    __syncthreads();
    float acc = 0.f;
    #pragma unroll 4
    for (int jj = 0; jj < KCH; jj++) acc += ych[jj] * w[(j0 + jj) * EMB + e];
    partial[((which * BGR + b) * NKC + kc) * EMB + e] = acc;
}

__global__ void k_fcred(const float* __restrict__ partial, const float* __restrict__ bias,
                        float* __restrict__ out) {
    int b = blockIdx.x;
    int e = threadIdx.x;
    const float* pg = partial + b * NKC * EMB + e;
    const float* pl = partial + (BGR + b) * NKC * EMB + e;
    float ag = bias[e], al = bias[e];
    #pragma unroll
    for (int k = 0; k < NKC; k++) { ag += pg[k * EMB]; al += pl[k * EMB]; }
    out[b * EMB + e] = 0.5f * (ag + al);
}

extern "C" void kernel_launch(void* const* d_in, const int* in_sizes, int n_in,
                              void* d_out, int out_size, void* d_ws, size_t ws_size,
                              hipStream_t stream) {
    const float* pro_x = (const float*)d_in[0];
    const int* eidx = (const int*)d_in[1];
    const int* esrc = eidx;
    const int* edst = eidx + N_EDGES;
    const float* pw = (const float*)d_in[2];
    const int* batch = (const int*)d_in[3];
    const int* rg = (const int*)d_in[4];
    const int* rl = (const int*)d_in[5];
    const float* g1_w1 = (const float*)d_in[6];
    const float* g1_b1 = (const float*)d_in[7];
    const float* g1_w2 = (const float*)d_in[8];
    const float* g1_b2 = (const float*)d_in[9];
    const float* g1_ew = (const float*)d_in[10];
    const float* g1_eb = (const float*)d_in[11];
    const float* g1_eps = (const float*)d_in[12];
    const float* g_w1 = (const float*)d_in[13];
    const float* g_b1 = (const float*)d_in[14];
    const float* g_w2 = (const float*)d_in[15];
    const float* g_b2 = (const float*)d_in[16];
    const float* g_ew = (const float*)d_in[17];
    const float* g_eb = (const float*)d_in[18];
    const float* g_eps = (const float*)d_in[19];
    const float* bn_gamma = (const float*)d_in[20];
    const float* bn_beta = (const float*)d_in[21];
    const float* fc1_xp_w = (const float*)d_in[22];
    const float* fc1_xp_b = (const float*)d_in[23];
    const float* emb1 = (const float*)d_in[24];
    const float* emb2 = (const float*)d_in[25];
    const float* convr1_w = (const float*)d_in[26];
    const float* convr1_b = (const float*)d_in[27];
    const float* convr2_w = (const float*)d_in[28];
    const float* convr2_b = (const float*)d_in[29];
    const float* fcxr_w = (const float*)d_in[30];
    const float* fcxr_b = (const float*)d_in[31];
    float* out = (float*)d_out;

    // persistent buffers
    float* wsf = (float*)d_ws;
    int* ptr       = (int*)wsf;        wsf += 100128;
    int* binoff    = (int*)wsf;        wsf += 512;
    int* bincur    = (int*)wsf;        wsf += 512;
    unsigned* er   = (unsigned*)wsf;   wsf += 2 * N_EDGES;
    float* stats   = wsf;              wsf += 1280;
    // union region
    float* un = wsf;
    int2* tmp_sw          = (int2*)un;
    int* bh               = (int*)(un + 7200000);
    __half* zh   = (__half*)(un + 1600000);
    __half* xh1  = (__half*)(un + 2400000);
    __half* xh32 = (__half*)(un + 4000000);
    float* bpart = un + 4100000;
    float* Wg    = un + 4300000;
    float* Wl    = un + 4382000;
    float* yg    = un + 5447000;
    float* yl    = un + 5695000;
    int* blg     = (int*)(un + 5961000);
    int* bll     = (int*)(un + 6153000);
    int* bpg     = (int*)(un + 6345000);
    int* bpl     = (int*)(un + 6346000);
    float* fcpart = un + 6360000;
    float* h      = un + 7400000;
    float* gsum   = stats;
    float* gcnt   = stats + 1024;
    float* bnstat = stats + 1088;

    hipMemsetAsync(stats, 0, 1280 * sizeof(float), stream);

    // CSR build
    k_bincnt<<<BCNT_BLK, 256, 0, stream>>>(edst, bh);
    k_binscan<<<1, 512, 0, stream>>>(bh, binoff, bincur);
    k_part1<<<P1_BLOCKS, 256, 0, stream>>>(esrc, edst, pw, bincur, tmp_sw);
    k_part2<<<NBIN, 256, 0, stream>>>(tmp_sw, binoff, er, ptr);

    // pro_x -> fp16 rows
    k_half1<<<(N_NODES * NFP + 255) / 256, 256, 0, stream>>>(pro_x, xh1, xh32);

    // RNA branch
    k_bucket<<<BGR, 256, 0, stream>>>(rg, MAXLEN, 5, blg, bpg);
    k_bucket<<<BGR, 256, 0, stream>>>(rl, LOCLEN, 65, bll, bpl);
    k_wsum<<<dim3(BGR, 5), 256, 0, stream>>>(blg, bpg, convr1_w, Wg, MAXLEN, 5);
    k_wsum<<<dim3(BGR, 65), 256, 0, stream>>>(bll, bpl, convr2_w, Wl, LOCLEN, 65);
    k_y<<<dim3(BGR * NF, 2), 128, 0, stream>>>(Wg, Wl, emb1, emb2, convr1_b, convr2_b, yg, yl);
    k_fcpart<<<dim3(BGR, 2, NKC), 128, 0, stream>>>(yg, yl, fcxr_w, fcpart);
    k_fcred<<<BGR, 128, 0, stream>>>(fcpart, fcxr_b, out);

    // GNN stack
    k_agg1<<<AGBLK, 256, 0, stream>>>(xh1, xh32, ptr, er, g1_ew, g1_eb, g1_eps, h);
    k_mlp1<<<MLPB, 256, 0, stream>>>(h, g1_w1, g1_b1, g1_w2, g1_b2, zh, bpart);
    k_bnred<<<1, 1024, 0, stream>>>(bpart, bnstat);
    for (int i = 0; i < 4; i++) {
        k_agg16<<<AGBLK, 256, 0, stream>>>(zh, ptr, er,
                                           g_ew + i * DIM, g_eb + i * DIM, g_eps + i,
                                           bnstat + i * 32, bn_gamma + i * DIM,
                                           bn_beta + i * DIM, h);
        k_mlp16<<<MLPB, 256, 0, stream>>>(h, g_w1 + i * DIM * DIM, g_b1 + i * DIM,
                                          g_w2 + i * DIM * DIM, g_b2 + i * DIM, zh, bpart);
        k_bnred<<<1, 1024, 0, stream>>>(bpart, bnstat + (i + 1) * 32);
    }
    k_pool<<<POOL_BLKS, 256, 0, stream>>>(zh, batch, bnstat + 4 * 32,
                                          bn_gamma + 4 * DIM, bn_beta + 4 * DIM, gsum, gcnt);
    k_xp<<<BGR, EMB, 0, stream>>>(gsum, gcnt, fc1_xp_w, fc1_xp_b, out + BGR * EMB);
}